// Round 16
// baseline (4278.508 us; speedup 1.0000x reference)
//
#include <hip/hip_runtime.h>

#define BB   32
#define DD   512
#define RR   4
#define MM   64
#define VV   10000
#define TT   64
#define IFX  3607
#define NNIN 2560
#define EPSF 1e-6f

typedef unsigned short u16;

__device__ __forceinline__ float bf(u16 u){ return __uint_as_float(((unsigned)u)<<16); }
__device__ __forceinline__ float4 b4f(ushort4 u){
  float4 f; f.x = bf(u.x); f.y = bf(u.y); f.z = bf(u.z); f.w = bf(u.w); return f;
}
__device__ __forceinline__ u16 f2b(float f){
  unsigned u = __float_as_uint(f);
  u += 0x7fffu + ((u>>16)&1u);
  return (u16)(u>>16);
}
__device__ __forceinline__ float sigmf(float x){ return 1.f/(1.f+__expf(-x)); }
__device__ __forceinline__ float softplusf(float x){ return x > 20.f ? x : log1pf(__expf(x)); }
__device__ __forceinline__ float wredSum(float v){
  #pragma unroll
  for (int s=1;s<64;s<<=1) v += __shfl_xor(v,s,64);
  return v;
}
__device__ __forceinline__ float wredMax(float v){
  #pragma unroll
  for (int s=1;s<64;s<<=1) v = fmaxf(v, __shfl_xor(v,s,64));
  return v;
}

// LLC-coherent scalar access (bypasses L2)
__device__ __forceinline__ float ldg_c(const float* p){
  return __hip_atomic_load(const_cast<float*>(p), __ATOMIC_RELAXED, __HIP_MEMORY_SCOPE_AGENT);
}
__device__ __forceinline__ void stg_c(float* p, float v){
  __hip_atomic_store(p, v, __ATOMIC_RELAXED, __HIP_MEMORY_SCOPE_AGENT);
}
__device__ __forceinline__ unsigned ldg_cu(const unsigned* p){
  return __hip_atomic_load(const_cast<unsigned*>(p), __ATOMIC_RELAXED, __HIP_MEMORY_SCOPE_AGENT);
}
__device__ __forceinline__ void stg_cu(unsigned* p, unsigned v){
  __hip_atomic_store(p, v, __ATOMIC_RELAXED, __HIP_MEMORY_SCOPE_AGENT);
}

// Batched LLC loads (issue + wait fused)
__device__ __forceinline__ void ldg_cv4x2(const float* p0,const float* p1, float4& a,float4& b){
  asm volatile("global_load_dwordx4 %0, %2, off sc0 sc1\n\t"
               "global_load_dwordx4 %1, %3, off sc0 sc1\n\t"
               "s_waitcnt vmcnt(0)"
               : "=&v"(a),"=&v"(b)
               : "v"(p0),"v"(p1)
               : "memory");
}
// T14 split: issue-early (no wait) ...
__device__ __forceinline__ void ldg_issue2(const float* p0,const float* p1, float4& a,float4& b){
  asm volatile("global_load_dwordx4 %0, %2, off sc0 sc1\n\t"
               "global_load_dwordx4 %1, %3, off sc0 sc1"
               : "=&v"(a),"=&v"(b)
               : "v"(p0),"v"(p1)
               : "memory");
}
// ... write-late fence. Consumers of the prefetched regs are LDS STORES
// (memory ops), which the "memory" clobber orders after this waitcnt.
__device__ __forceinline__ void ld_fence(){
  asm volatile("s_waitcnt vmcnt(0)" ::: "memory");
}
__device__ __forceinline__ void ldg_c4s(const float* p0,const float* p1,const float* p2,const float* p3,
                                        float& a,float& b,float& c,float& d){
  asm volatile("global_load_dword %0, %4, off sc0 sc1\n\t"
               "global_load_dword %1, %5, off sc0 sc1\n\t"
               "global_load_dword %2, %6, off sc0 sc1\n\t"
               "global_load_dword %3, %7, off sc0 sc1\n\t"
               "s_waitcnt vmcnt(0)"
               : "=&v"(a),"=&v"(b),"=&v"(c),"=&v"(d)
               : "v"(p0),"v"(p1),"v"(p2),"v"(p3)
               : "memory");
}
__device__ __forceinline__ void ldg_c2s(const float* p0,const float* p1, float& a,float& b){
  asm volatile("global_load_dword %0, %2, off sc0 sc1\n\t"
               "global_load_dword %1, %3, off sc0 sc1\n\t"
               "s_waitcnt vmcnt(0)"
               : "=&v"(a),"=&v"(b)
               : "v"(p0),"v"(p1)
               : "memory");
}

#define SM_FLOATS 9600
#define NBLK 256u
#define NTHR 512

// ---- grid barrier v5 (512-thread blocks): flag stores, master gathers ----
__device__ __forceinline__ void gbar5(unsigned* flags, unsigned* gen, unsigned ep){
  asm volatile("s_waitcnt vmcnt(0) lgkmcnt(0)" ::: "memory");
  __syncthreads();
  if (threadIdx.x == 0) stg_cu(&flags[blockIdx.x*16], ep);
  if (blockIdx.x == 0) {
    if (threadIdx.x < 256) {
      const unsigned* f = &flags[threadIdx.x*16];
      while (ldg_cu(f) < ep) __builtin_amdgcn_s_sleep(1);
    }
    __syncthreads();
    if (threadIdx.x == 0) stg_cu(gen, ep);
  } else if (threadIdx.x == 0) {
    while (ldg_cu(gen) < ep) __builtin_amdgcn_s_sleep(1);
  }
  __syncthreads();
}

// =============== persistent-W LDS layouts ===============
#define LW_OFF 5312
#define XW_OFF 4224

__device__ __forceinline__ void preload_lstm(float* S, int tile,
    const float* __restrict__ Wx, int wx_stride, const float* __restrict__ Wh)
{
  float* WL = S + LW_OFF;
  const int tid = threadIdx.x;
  const int dblk = tile*8;
  for (int i = tid; i < 8192; i += NTHR) {
    const int r  = i >> 8;
    const int k4 = (i & 255) * 4;
    const int gr = ((r>>3)<<9) + dblk + (r&7);
    float4 v;
    if (k4 < 512) v = *(const float4*)&Wx[(size_t)gr*wx_stride + k4];
    else          v = *(const float4*)&Wh[(size_t)gr*512 + (k4-512)];
    *(float4*)&WL[r*1028 + k4] = v;
  }
}

__device__ __forceinline__ void preload_xi(float* S, int xtile, const float* __restrict__ Wi){
  float* XW = S + XW_OFF;
  const int tid = threadIdx.x;
  for (int i = tid; i < 8192; i += NTHR) {
    const int r  = i >> 7;
    const int k4 = (i & 127) * 4;
    int cr = xtile*64 + r; if (cr >= IFX) cr = IFX-1;
    *(float4*)&XW[r*516 + k4] = *(const float4*)&Wi[(size_t)cr*512 + k4];
  }
}

// ---- LSTM gates GEMM (persistent W, 512 thr, conflict-free lane map) ----
// c = tid>>4 : 4 distinct W rows/wave, 16-lane broadcast, banks 4c+K distinct.
// batches {b2, b2+16}, b2 = tid&15 : As rows 2-way bank alias (free).
__device__ __noinline__ void lstm_tile_p(
    float* S, int tile,
    const float* __restrict__ bx, const float* __restrict__ bh,
    const float* emb, const int* seq, int t,
    const float* xf,
    const float* hprev, float* hcur,
    float* cst, float* outc, u16* full)
{
  float (*As)[132] = (float(*)[132])S;
  float* gs = S + 4224;
  int* idxs = (int*)(S + 5280);
  const float* WL = S + LW_OFF;
  const int tid = threadIdx.x;
  const int c  = tid >> 4;          // gate-col 0..31
  const int b2 = tid & 15;          // batches b2, b2+16
  const int dblk = tile * 8;
  const int gcol = ((c>>3)<<9) + dblk + (c&7);
  const int ba = tid >> 5;          // staging batch a (0..15)
  const int bbs = ba + 16;          // staging batch b (16..31)
  const int f0 = (tid & 31) * 4;    // staging f4 offset
  float a0p=0.f, a0q=0.f, a1p=0.f, a1q=0.f;
  if (emb != nullptr && tid < 32) idxs[tid] = seq[tid*64 + t];
  __syncthreads();
  #define LSRC(ch, bb_) ( ((ch) < 4) \
      ? ((emb != nullptr) ? &emb[(size_t)idxs[bb_]*512 + (ch)*128 + f0] \
                          : &xf[(bb_)*512 + (ch)*128 + f0]) \
      : &hprev[(bb_)*512 + ((ch)*128 - 512) + f0] )
  float4 v0, v1;
  ldg_cv4x2(LSRC(0,ba), LSRC(0,bbs), v0, v1);
  *(float4*)&As[ba][f0]  = v0;
  *(float4*)&As[bbs][f0] = v1;
  __syncthreads();
  for (int chunk = 0; chunk < 8; ++chunk) {
    if (chunk < 7) ldg_issue2(LSRC(chunk+1,ba), LSRC(chunk+1,bbs), v0, v1);
    const float* Wr = WL + c*1028 + chunk*128;
    #pragma unroll 8
    for (int kk = 0; kk < 128; kk += 4) {
      const float4 w4 = *(const float4*)&Wr[kk];
      const float4 x0 = *(const float4*)&As[b2][kk];
      const float4 x1 = *(const float4*)&As[b2+16][kk];
      a0p = fmaf(x0.x,w4.x, fmaf(x0.y,w4.y, a0p));
      a0q = fmaf(x0.z,w4.z, fmaf(x0.w,w4.w, a0q));
      a1p = fmaf(x1.x,w4.x, fmaf(x1.y,w4.y, a1p));
      a1q = fmaf(x1.z,w4.z, fmaf(x1.w,w4.w, a1q));
    }
    __syncthreads();
    if (chunk < 7) {
      ld_fence();
      *(float4*)&As[ba][f0]  = v0;
      *(float4*)&As[bbs][f0] = v1;
    }
    __syncthreads();
  }
  #undef LSRC
  const float bias = bx[gcol] + bh[gcol];
  gs[c*33 + b2]      = a0p + a0q + bias;
  gs[c*33 + b2 + 16] = a1p + a1q + bias;
  __syncthreads();
  if (tid < 256) {
    const int bb2 = tid & 31, dl2 = tid >> 5;
    const float gi = gs[(0*8+dl2)*33 + bb2];
    const float gf = gs[(1*8+dl2)*33 + bb2];
    const float gg = gs[(2*8+dl2)*33 + bb2];
    const float go = gs[(3*8+dl2)*33 + bb2];
    const int d = dblk + dl2;
    const int cid = bb2*512 + d;
    const float cv = sigmf(gf)*cst[cid] + sigmf(gi)*tanhf(gg);
    const float hv = sigmf(go)*tanhf(cv);
    cst[cid] = cv;
    stg_c(&hcur[cid], hv);
    if (outc != nullptr) {
      const float oc = fminf(fmaxf(hv,-20.f),20.f);
      stg_c(&outc[cid], oc);
      if (full != nullptr) full[((size_t)t*32 + bb2)*2560 + d] = f2b(oc);
    }
  }
  __syncthreads();
}

// ---- xi tile (persistent W, 512 thr, conflict-free lane map) ----
// c = tid>>3 : 8 distinct W rows/wave, 8-lane broadcast, banks distinct.
// batches {bq+8m}, bq = tid&7 : As banks 4bq distinct per instr.
__device__ __noinline__ void xi_tile_p(
    float* S, int xtile,
    const float* outc, const float* __restrict__ bi, float* xi)
{
  float (*As)[132] = (float(*)[132])S;
  const float* XW = S + XW_OFF;
  const int tid = threadIdx.x;
  const int c  = tid >> 3;          // 0..63
  const int bq = tid & 7;           // batches bq + 8m, m=0..3
  const int col = xtile*64 + c;
  const int ba = tid >> 5;
  const int bbs = ba + 16;
  const int f0 = (tid & 31) * 4;
  float accp[4], accq[4];
  #pragma unroll
  for (int j=0;j<4;j++){ accp[j]=0.f; accq[j]=0.f; }
  float4 v0, v1;
  ldg_cv4x2(&outc[ba*512 + f0], &outc[bbs*512 + f0], v0, v1);
  *(float4*)&As[ba][f0]  = v0;
  *(float4*)&As[bbs][f0] = v1;
  __syncthreads();
  for (int chunk = 0; chunk < 4; ++chunk) {
    if (chunk < 3) {
      const int kn = (chunk+1)*128;
      ldg_issue2(&outc[ba*512 + kn + f0], &outc[bbs*512 + kn + f0], v0, v1);
    }
    const float* Wr = XW + c*516 + chunk*128;
    #pragma unroll 4
    for (int kk = 0; kk < 128; kk += 4) {
      const float4 w4 = *(const float4*)&Wr[kk];
      #pragma unroll
      for (int m=0;m<4;m++){
        const float4 a = *(const float4*)&As[bq + 8*m][kk];
        accp[m] = fmaf(a.x,w4.x, fmaf(a.y,w4.y, accp[m]));
        accq[m] = fmaf(a.z,w4.z, fmaf(a.w,w4.w, accq[m]));
      }
    }
    __syncthreads();
    if (chunk < 3) {
      ld_fence();
      *(float4*)&As[ba][f0]  = v0;
      *(float4*)&As[bbs][f0] = v1;
    }
    __syncthreads();
  }
  if (col < IFX) {
    const float bias = bi[col];
    #pragma unroll
    for (int m=0;m<4;m++)
      stg_c(&xi[(size_t)(bq + 8*m)*IFX + col], accp[m] + accq[m] + bias);
  }
  __syncthreads();
}

__device__ __constant__ int kSidx[23] = {
  2048,2049,2050,2051, 2564, 3589,3590,3591,3592, 3593, 3594,
  3595,3596,3597, 3598,3599,3600, 3601,3602,3603, 3604,3605,3606
};

// ===================== LDS-persistent DNC memory step (512 thr) =====================
#define MEMPITCH 516
#define L_MEM   0
#define L_LINK  33024
#define L_RK    37184
#define L_WK    39232
#define L_RWP   39744
#define L_PREC  40000
#define L_USAGE 40064
#define L_WCW   40128
#define L_U     40192
#define L_WW    40256
#define L_CWA   40320
#define L_SC    40576
#define L_SRAW  40616
#define L_END   40640
#define DYN_LDS_BYTES 162560

__device__ __noinline__ void mem_tile_lds(
    float* S, int b, const float* xi, u16* full, int t)
{
  const int tid = threadIdx.x;
  const float* xb = xi + (size_t)b*IFX;
  float* MEMS = S + L_MEM;
  float* LNK  = S + L_LINK;
  float (*rk_s)[512] = (float(*)[512])(S + L_RK);
  float* wk_s  = S + L_WK;
  float* RWP   = S + L_RWP;
  float* PREC  = S + L_PREC;
  float* USAGE = S + L_USAGE;
  float* wcw_s = S + L_WCW;
  float* u_s   = S + L_U;
  float* WW    = S + L_WW;
  float* sorted_s = S + L_CWA;
  float* excl_s   = S + L_CWA + 64;
  int*   rank_s   = (int*)(S + L_CWA + 128);
  float (*cw_s)[64] = (float(*)[64])(S + L_CWA);
  float* sc   = S + L_SC;
  float* sraw = S + L_SRAW;

  {
    const float* base = xb + tid*4;
    float v0,v1,v2,v3;
    ldg_c4s(base+0,base+1,base+2,base+3, v0,v1,v2,v3);
    float* d = &rk_s[tid>>7][(tid&127)*4];
    d[0]=tanhf(v0); d[1]=tanhf(v1); d[2]=tanhf(v2); d[3]=tanhf(v3);
  }
  if (tid < 128) {
    const float* base = xb + 2052 + tid*4;
    float v0,v1,v2,v3;
    ldg_c4s(base+0,base+1,base+2,base+3, v0,v1,v2,v3);
    float* d = &wk_s[tid*4];
    d[0]=tanhf(v0); d[1]=tanhf(v1); d[2]=tanhf(v2); d[3]=tanhf(v3);
  }
  if (tid < 23) sraw[tid] = ldg_c(&xb[kSidx[tid]]);
  __syncthreads();
  if (tid == 0) {
    for (int r=0;r<4;r++) sc[r] = softplusf(sraw[r]);
    sc[4] = softplusf(sraw[4]);
    for (int r=0;r<4;r++) sc[5+r] = sigmf(sraw[5+r]);
    sc[9]  = sigmf(sraw[9]);
    sc[10] = sigmf(sraw[10]);
    for (int r=0;r<4;r++) {
      const float a0=sraw[11+3*r], a1=sraw[12+3*r], a2=sraw[13+3*r];
      const float mx=fmaxf(a0,fmaxf(a1,a2));
      const float e0=__expf(a0-mx), e1=__expf(a1-mx), e2=__expf(a2-mx);
      const float s=e0+e1+e2;
      sc[11+3*r]=e0/s; sc[12+3*r]=e1/s; sc[13+3*r]=e2/s;
    }
  }
  if (tid < 256) {
    const int wid = tid>>6, ln = tid&63;
    float p = 0.f;
    for (int i = ln; i < 512; i += 64) { const float v = rk_s[wid][i]; p = fmaf(v,v,p); }
    p = wredSum(p);
    if (ln == 0) sc[24+wid] = sqrtf(p);
    if (wid == 1) {
      float q2 = 0.f;
      for (int i = ln; i < 512; i += 64) { const float v = wk_s[i]; q2 = fmaf(v,v,q2); }
      q2 = wredSum(q2);
      if (ln == 0) sc[23] = sqrtf(q2);
    }
  }
  __syncthreads();
  if (tid < 256) {
    const int m = tid>>2, q = tid&3;
    const float* mr = MEMS + m*MEMPITCH;
    float d = 0.f, ss = 0.f;
    for (int i = q*128; i < q*128+128; i += 4) {
      const float4 mv = *(const float4*)&mr[i];
      d = fmaf(mv.x, wk_s[i  ], d); d = fmaf(mv.y, wk_s[i+1], d);
      d = fmaf(mv.z, wk_s[i+2], d); d = fmaf(mv.w, wk_s[i+3], d);
      ss = fmaf(mv.x,mv.x,ss); ss = fmaf(mv.y,mv.y,ss);
      ss = fmaf(mv.z,mv.z,ss); ss = fmaf(mv.w,mv.w,ss);
    }
    d  += __shfl_xor(d,1,64);  d  += __shfl_xor(d,2,64);
    ss += __shfl_xor(ss,1,64); ss += __shfl_xor(ss,2,64);
    if (q == 0) wcw_s[m] = d / ((sqrtf(ss)+EPSF)*(sc[23]+EPSF)) * sc[4];
  }
  if (tid < 64) {
    const float uo = USAGE[tid];
    float u = uo + (1.f-uo)*WW[tid];
    #pragma unroll
    for (int r=0;r<4;r++) u *= (1.f - sc[5+r]*RWP[r*64+tid]);
    USAGE[tid] = u;
  }
  __syncthreads();
  if (tid < 64) {
    const float v = wcw_s[tid];
    const float mx = wredMax(v);
    const float e = __expf(v-mx);
    const float s2 = wredSum(e);
    wcw_s[tid] = e/s2;
    u_s[tid] = EPSF + (1.f-EPSF)*USAGE[tid];
  }
  __syncthreads();
  if (tid < 64) {
    const float u = u_s[tid]; int rk2 = 0;
    for (int j=0;j<64;j++){ const float uj = u_s[j]; rk2 += (uj<u) || (uj==u && j<tid); }
    rank_s[tid] = rk2; sorted_s[rk2] = u;
  }
  __syncthreads();
  if (tid == 0) { float run = 1.f; for (int p2=0;p2<64;p2++){ excl_s[p2]=run; run*=sorted_s[p2]; } }
  __syncthreads();
  if (tid < 64) {
    const float al = (1.f - u_s[tid]) * excl_s[rank_s[tid]];
    const float wwv = sc[10]*(sc[9]*al + (1.f-sc[9])*wcw_s[tid]);
    WW[tid] = wwv;
    const float s3 = wredSum(wwv);
    if (tid==0) sc[28] = s3;
  }
  __syncthreads();
  {
    float e0,w0;
    ldg_c2s(&xb[2565+tid], &xb[3077+tid], e0, w0);
    const float er0 = sigmf(e0);
    const float wv0 = tanhf(w0);
    #pragma unroll 4
    for (int m=0;m<64;m++){
      const float wwm = WW[m];
      float* p = MEMS + m*MEMPITCH + tid;
      p[0] = p[0]*(1.f - wwm*er0) + wwm*wv0;
    }
  }
  __syncthreads();
  for (int e = tid; e < 4096; e += NTHR) {
    const int i2 = e>>6, j2 = e&63;
    const float lv = LNK[i2*65+j2];
    LNK[i2*65+j2] = (i2==j2) ? 0.f
               : ((1.f - WW[i2] - WW[j2])*lv + WW[i2]*PREC[j2]);
  }
  __syncthreads();
  if (tid < 64) PREC[tid] = (1.f - sc[28])*PREC[tid] + WW[tid];
  __syncthreads();
  const int r6 = tid>>6, m6 = tid&63;
  if (tid < 256) {
    const float* mr = MEMS + m6*MEMPITCH;
    const float* rkr = rk_s[r6];
    float d = 0.f, ss = 0.f;
    for (int i=0;i<512;i+=4){
      const float4 mv = *(const float4*)&mr[i];
      d = fmaf(mv.x, rkr[i  ], d); d = fmaf(mv.y, rkr[i+1], d);
      d = fmaf(mv.z, rkr[i+2], d); d = fmaf(mv.w, rkr[i+3], d);
      ss = fmaf(mv.x,mv.x,ss); ss = fmaf(mv.y,mv.y,ss);
      ss = fmaf(mv.z,mv.z,ss); ss = fmaf(mv.w,mv.w,ss);
    }
    const float cv = d / ((sqrtf(ss)+EPSF)*(sc[24+r6]+EPSF)) * sc[r6];
    const float mx = wredMax(cv);
    const float e = __expf(cv-mx);
    const float s2 = wredSum(e);
    cw_s[r6][m6] = e/s2;
  }
  __syncthreads();
  float rn = 0.f;
  if (tid < 256) {
    float fw = 0.f, bw = 0.f;
    #pragma unroll 8
    for (int m3=0;m3<64;m3++){
      const float rp = RWP[r6*64+m3];
      fw = fmaf(LNK[m6*65+m3], rp, fw);
      bw = fmaf(LNK[m3*65+m6], rp, bw);
    }
    rn = sc[11+3*r6]*bw + sc[12+3*r6]*fw + sc[13+3*r6]*cw_s[r6][m6];
  }
  __syncthreads();
  if (tid < 256) RWP[r6*64+m6] = rn;
  __syncthreads();
  if (full != nullptr && tid < 256) {
    const int l = tid&63, r8 = tid>>6;
    float a[8];
    #pragma unroll
    for (int j=0;j<8;j++) a[j]=0.f;
    for (int m3=0;m3<64;m3++){
      const float rv_ = RWP[r8*64+m3];
      const float* mr = MEMS + m3*MEMPITCH + 2*l;
      #pragma unroll
      for (int j=0;j<4;j++){
        const float2 v = *(const float2*)&mr[128*j];
        a[2*j]   = fmaf(rv_, v.x, a[2*j]);
        a[2*j+1] = fmaf(rv_, v.y, a[2*j+1]);
      }
    }
    u16* dst = full + ((size_t)t*32 + b)*2560 + 512 + r8*512;
    #pragma unroll
    for (int j=0;j<4;j++){
      const unsigned wd = (unsigned)f2b(a[2*j]) | ((unsigned)f2b(a[2*j+1])<<16);
      *(unsigned*)&dst[2*l + 128*j] = wd;
    }
  }
  __syncthreads();
}

// ======= fallback-path tiles (round-4-verified, 256 thr, global W) =======
__device__ __noinline__ void lstm_tile_g(
    float* sm, int tile,
    const float* __restrict__ Wx, int wx_stride,
    const float* __restrict__ Wh,
    const float* __restrict__ bx, const float* __restrict__ bh,
    const float* emb, const int* seq, int t,
    const float* xf,
    const float* hprev, float* hcur,
    float* cst, float* outc, u16* full)
{
  float (*As)[132] = (float(*)[132])sm;
  float (*Ws)[132] = (float(*)[132])(sm + 4224);
  float* gs = sm + 8448;
  int* idxs = (int*)(sm + 9504);
  const int tid = threadIdx.x;
  const int c = tid & 31;
  const int dblk = tile * 8;
  const int gcol = ((c>>3)<<9) + dblk + (c&7);
  const int b0 = (tid >> 5) * 4;
  float acc0=0.f, acc1=0.f, acc2=0.f, acc3=0.f;
  if (emb != nullptr && tid < 32) idxs[tid] = seq[tid*64 + t];
  __syncthreads();
  for (int chunk = 0; chunk < 8; ++chunk) {
    const int k0 = chunk * 128;
    const bool xp = (chunk < 4);
    for (int i = tid; i < 1024; i += 256) {
      const int bb2 = i >> 5, f4i = (i & 31)*4;
      if (xp && emb != nullptr) {
        *(float4*)&As[bb2][f4i] = *(const float4*)&emb[(size_t)idxs[bb2]*512 + k0 + f4i];
      } else {
        const float* src = xp ? &xf[bb2*512 + k0 + f4i]
                              : &hprev[bb2*512 + (k0-512) + f4i];
        As[bb2][f4i+0] = ldg_c(src+0);
        As[bb2][f4i+1] = ldg_c(src+1);
        As[bb2][f4i+2] = ldg_c(src+2);
        As[bb2][f4i+3] = ldg_c(src+3);
      }
    }
    for (int i = tid; i < 1024; i += 256) {
      const int r = i >> 5, f4i = (i & 31)*4;
      const int gr = ((r>>3)<<9) + dblk + (r&7);
      const float4 v = xp ? *(const float4*)&Wx[(size_t)gr*wx_stride + k0 + f4i]
                          : *(const float4*)&Wh[(size_t)gr*512 + (k0-512) + f4i];
      *(float4*)&Ws[r][f4i] = v;
    }
    __syncthreads();
    #pragma unroll 8
    for (int kk = 0; kk < 128; kk += 4) {
      const float4 w4 = *(const float4*)&Ws[c][kk];
      const float4 a0 = *(const float4*)&As[b0+0][kk];
      const float4 a1 = *(const float4*)&As[b0+1][kk];
      const float4 a2 = *(const float4*)&As[b0+2][kk];
      const float4 a3 = *(const float4*)&As[b0+3][kk];
      acc0 = fmaf(a0.x,w4.x,fmaf(a0.y,w4.y,fmaf(a0.z,w4.z,fmaf(a0.w,w4.w,acc0))));
      acc1 = fmaf(a1.x,w4.x,fmaf(a1.y,w4.y,fmaf(a1.z,w4.z,fmaf(a1.w,w4.w,acc1))));
      acc2 = fmaf(a2.x,w4.x,fmaf(a2.y,w4.y,fmaf(a2.z,w4.z,fmaf(a2.w,w4.w,acc2))));
      acc3 = fmaf(a3.x,w4.x,fmaf(a3.y,w4.y,fmaf(a3.z,w4.z,fmaf(a3.w,w4.w,acc3))));
    }
    __syncthreads();
  }
  const float bias = bx[gcol] + bh[gcol];
  gs[c*33 + b0+0] = acc0 + bias;
  gs[c*33 + b0+1] = acc1 + bias;
  gs[c*33 + b0+2] = acc2 + bias;
  gs[c*33 + b0+3] = acc3 + bias;
  __syncthreads();
  {
    const int b2 = tid & 31, dl2 = tid >> 5;
    const float gi = gs[(0*8+dl2)*33 + b2];
    const float gf = gs[(1*8+dl2)*33 + b2];
    const float gg = gs[(2*8+dl2)*33 + b2];
    const float go = gs[(3*8+dl2)*33 + b2];
    const int d = dblk + dl2;
    const int cid = b2*512 + d;
    const float cv = sigmf(gf)*cst[cid] + sigmf(gi)*tanhf(gg);
    const float hv = sigmf(go)*tanhf(cv);
    cst[cid] = cv;
    stg_c(&hcur[cid], hv);
    if (outc != nullptr) {
      const float oc = fminf(fmaxf(hv,-20.f),20.f);
      stg_c(&outc[cid], oc);
      if (full != nullptr) full[((size_t)t*32 + b2)*2560 + d] = f2b(oc);
    }
  }
  __syncthreads();
}

__device__ __noinline__ void xi_tile_g(
    float* sm, int tile,
    const float* outc,
    const float* __restrict__ Wi, const float* __restrict__ bi,
    float* xi)
{
  float (*As)[132] = (float(*)[132])sm;
  float (*Ws)[132] = (float(*)[132])(sm + 4224);
  const int tid = threadIdx.x;
  const int c = tid & 31;
  const int col = tile*32 + c;
  const int b0 = (tid>>5)*4;
  float acc0=0.f,acc1=0.f,acc2=0.f,acc3=0.f;
  for (int chunk = 0; chunk < 4; ++chunk) {
    const int k0 = chunk*128;
    for (int i = tid; i < 1024; i += 256) {
      const int bb2 = i>>5, f4i = (i&31)*4;
      const float* src = &outc[bb2*512 + k0 + f4i];
      As[bb2][f4i+0] = ldg_c(src+0);
      As[bb2][f4i+1] = ldg_c(src+1);
      As[bb2][f4i+2] = ldg_c(src+2);
      As[bb2][f4i+3] = ldg_c(src+3);
    }
    for (int i = tid; i < 1024; i += 256) {
      const int r = i>>5, f4i = (i&31)*4;
      int cr = tile*32 + r; cr = cr < IFX ? cr : IFX-1;
      *(float4*)&Ws[r][f4i] = *(const float4*)&Wi[(size_t)cr*512 + k0 + f4i];
    }
    __syncthreads();
    #pragma unroll 8
    for (int kk = 0; kk < 128; kk += 4) {
      const float4 w4 = *(const float4*)&Ws[c][kk];
      const float4 a0 = *(const float4*)&As[b0+0][kk];
      const float4 a1 = *(const float4*)&As[b0+1][kk];
      const float4 a2 = *(const float4*)&As[b0+2][kk];
      const float4 a3 = *(const float4*)&As[b0+3][kk];
      acc0 = fmaf(a0.x,w4.x,fmaf(a0.y,w4.y,fmaf(a0.z,w4.z,fmaf(a0.w,w4.w,acc0))));
      acc1 = fmaf(a1.x,w4.x,fmaf(a1.y,w4.y,fmaf(a1.z,w4.z,fmaf(a1.w,w4.w,acc1))));
      acc2 = fmaf(a2.x,w4.x,fmaf(a2.y,w4.y,fmaf(a2.z,w4.z,fmaf(a2.w,w4.w,acc2))));
      acc3 = fmaf(a3.x,w4.x,fmaf(a3.y,w4.y,fmaf(a3.z,w4.z,fmaf(a3.w,w4.w,acc3))));
    }
    __syncthreads();
  }
  if (col < IFX) {
    const float bias = bi[col];
    stg_c(&xi[(size_t)(b0+0)*IFX + col], acc0 + bias);
    stg_c(&xi[(size_t)(b0+1)*IFX + col], acc1 + bias);
    stg_c(&xi[(size_t)(b0+2)*IFX + col], acc2 + bias);
    stg_c(&xi[(size_t)(b0+3)*IFX + col], acc3 + bias);
  }
  __syncthreads();
}

__device__ __noinline__ void mem_tile_g(
    float* sm, int b,
    const float* xi,
    float* mem,
    float* link, float* prec,
    float* rwg, float* wwg, float* usg,
    u16* full, int t)
{
  const int tid = threadIdx.x;
  const float* xb = xi + (size_t)b*IFX;
  float (*rk_s)[512]  = (float(*)[512])sm;
  float* wk_s   = sm + 2048;
  float* er_s   = sm + 2560;
  float* wv_s   = sm + 3072;
  float (*rwp_s)[64]  = (float(*)[64])(sm + 3584);
  float* prec_s = sm + 3840;
  float* usage_s= sm + 3904;
  float* wcw_s  = sm + 3968;
  float* u_s    = sm + 4032;
  float* ww_s   = sm + 4096;
  float* sorted_s = sm + 4160;
  float* excl_s = sm + 4224;
  int*   rank_s = (int*)(sm + 4288);
  float (*cw_s)[64]  = (float(*)[64])(sm + 4352);
  float (*rwn_s)[64] = (float(*)[64])(sm + 4608);
  float* mn_s   = sm + 4864;
  float* sc     = sm + 4928;
  float (*link_s)[65] = (float(*)[65])(sm + 4976);

  for (int i = tid; i < 2048; i += 256) rk_s[i>>9][i&511] = tanhf(ldg_c(&xb[i]));
  for (int i = tid; i < 512; i += 256) {
    wk_s[i] = tanhf(ldg_c(&xb[2052+i]));
    er_s[i] = sigmf(ldg_c(&xb[2565+i]));
    wv_s[i] = tanhf(ldg_c(&xb[3077+i]));
  }
  rwp_s[tid>>6][tid&63] = rwg[b*256 + tid];
  if (tid < 64) { prec_s[tid] = prec[b*64+tid]; usage_s[tid] = usg[b*64+tid]; }
  if (tid == 0) {
    for (int r=0;r<4;r++) sc[r] = softplusf(ldg_c(&xb[2048+r]));
    sc[4] = softplusf(ldg_c(&xb[2564]));
    for (int r=0;r<4;r++) sc[5+r] = sigmf(ldg_c(&xb[3589+r]));
    sc[9]  = sigmf(ldg_c(&xb[3593]));
    sc[10] = sigmf(ldg_c(&xb[3594]));
    for (int r=0;r<4;r++) {
      const float a0=ldg_c(&xb[3595+3*r]), a1=ldg_c(&xb[3596+3*r]), a2=ldg_c(&xb[3597+3*r]);
      const float mx=fmaxf(a0,fmaxf(a1,a2));
      const float e0=__expf(a0-mx), e1=__expf(a1-mx), e2=__expf(a2-mx);
      const float s=e0+e1+e2;
      sc[11+3*r]=e0/s; sc[12+3*r]=e1/s; sc[13+3*r]=e2/s;
    }
  }
  __syncthreads();
  {
    const int wid = tid>>6, ln = tid&63;
    float p = 0.f;
    for (int i = ln; i < 512; i += 64) { const float v = rk_s[wid][i]; p = fmaf(v,v,p); }
    p = wredSum(p);
    if (ln == 0) sc[24+wid] = sqrtf(p);
    if (wid == 1) {
      float q2 = 0.f;
      for (int i = ln; i < 512; i += 64) { const float v = wk_s[i]; q2 = fmaf(v,v,q2); }
      q2 = wredSum(q2);
      if (ln == 0) sc[23] = sqrtf(q2);
    }
  }
  __syncthreads();
  {
    const int m = tid>>2, q = tid&3;
    const float* mr = mem + ((size_t)b*64 + m)*512;
    float d = 0.f, ss = 0.f;
    for (int i = q*128; i < q*128+128; i += 4) {
      const float4 mv = *(const float4*)&mr[i];
      d = fmaf(mv.x, wk_s[i  ], d); d = fmaf(mv.y, wk_s[i+1], d);
      d = fmaf(mv.z, wk_s[i+2], d); d = fmaf(mv.w, wk_s[i+3], d);
      ss = fmaf(mv.x,mv.x,ss); ss = fmaf(mv.y,mv.y,ss);
      ss = fmaf(mv.z,mv.z,ss); ss = fmaf(mv.w,mv.w,ss);
    }
    d  += __shfl_xor(d,1,64);  d  += __shfl_xor(d,2,64);
    ss += __shfl_xor(ss,1,64); ss += __shfl_xor(ss,2,64);
    if (q == 0) wcw_s[m] = d / ((sqrtf(ss)+EPSF)*(sc[23]+EPSF)) * sc[4];
  }
  if (tid < 64) {
    const float uo = usage_s[tid];
    const float wwp = wwg[b*64+tid];
    float u = uo + (1.f-uo)*wwp;
    #pragma unroll
    for (int r=0;r<4;r++) u *= (1.f - sc[5+r]*rwp_s[r][tid]);
    usage_s[tid] = u; usg[b*64+tid] = u;
  }
  __syncthreads();
  if (tid < 64) {
    const float v = wcw_s[tid];
    const float mx = wredMax(v);
    const float e = __expf(v-mx);
    const float s2 = wredSum(e);
    wcw_s[tid] = e/s2;
    u_s[tid] = EPSF + (1.f-EPSF)*usage_s[tid];
  }
  __syncthreads();
  if (tid < 64) {
    const float u = u_s[tid]; int rk2 = 0;
    for (int j=0;j<64;j++){ const float uj = u_s[j]; rk2 += (uj<u) || (uj==u && j<tid); }
    rank_s[tid] = rk2; sorted_s[rk2] = u;
  }
  __syncthreads();
  if (tid == 0) { float run = 1.f; for (int p2=0;p2<64;p2++){ excl_s[p2]=run; run*=sorted_s[p2]; } }
  __syncthreads();
  if (tid < 64) {
    const float al = (1.f - u_s[tid]) * excl_s[rank_s[tid]];
    const float wwv = sc[10]*(sc[9]*al + (1.f-sc[9])*wcw_s[tid]);
    ww_s[tid] = wwv; wwg[b*64+tid] = wwv;
    const float s3 = wredSum(wwv);
    if (tid==0) sc[28] = s3;
  }
  __syncthreads();
  {
    const int m = tid>>2, q = tid&3;
    const float wwm = ww_s[m];
    float* mr = mem + ((size_t)b*64 + m)*512;
    float ss = 0.f;
    for (int i = q*128; i < q*128+128; i += 4) {
      float4 mv = *(const float4*)&mr[i];
      mv.x = mv.x*(1.f - wwm*er_s[i  ]) + wwm*wv_s[i  ];
      mv.y = mv.y*(1.f - wwm*er_s[i+1]) + wwm*wv_s[i+1];
      mv.z = mv.z*(1.f - wwm*er_s[i+2]) + wwm*wv_s[i+2];
      mv.w = mv.w*(1.f - wwm*er_s[i+3]) + wwm*wv_s[i+3];
      *(float4*)&mr[i] = mv;
      ss += mv.x*mv.x + mv.y*mv.y + mv.z*mv.z + mv.w*mv.w;
    }
    ss += __shfl_xor(ss,1,64); ss += __shfl_xor(ss,2,64);
    if (q==0) mn_s[m] = sqrtf(ss);
  }
  __syncthreads();
  {
    float* lrow = link + (size_t)b*4096;
    for (int e = tid; e < 4096; e += 256) {
      const int i2 = e>>6, j2 = e&63;
      const float ln2 = (i2==j2) ? 0.f
                 : ((1.f - ww_s[i2] - ww_s[j2])*lrow[e] + ww_s[i2]*prec_s[j2]);
      link_s[i2][j2] = ln2;
      lrow[e] = ln2;
    }
  }
  if (tid < 64) prec[b*64+tid] = (1.f - sc[28])*prec_s[tid] + ww_s[tid];
  __syncthreads();
  const int r6 = tid>>6, m6 = tid&63;
  {
    const float* mr = mem + ((size_t)b*64 + m6)*512;
    const float* rkr = rk_s[r6];
    float d = 0.f;
    for (int i=0;i<512;i+=4){
      const float4 mv = *(const float4*)&mr[i];
      d = fmaf(mv.x, rkr[i  ], d); d = fmaf(mv.y, rkr[i+1], d);
      d = fmaf(mv.z, rkr[i+2], d); d = fmaf(mv.w, rkr[i+3], d);
    }
    const float cv = d / ((mn_s[m6]+EPSF)*(sc[24+r6]+EPSF)) * sc[r6];
    const float mx = wredMax(cv);
    const float e = __expf(cv-mx);
    const float s2 = wredSum(e);
    cw_s[r6][m6] = e/s2;
  }
  __syncthreads();
  {
    float fw = 0.f, bw = 0.f;
    #pragma unroll 8
    for (int m3=0;m3<64;m3++){
      const float rp = rwp_s[r6][m3];
      fw = fmaf(link_s[m6][m3], rp, fw);
      bw = fmaf(link_s[m3][m6], rp, bw);
    }
    const float rn = sc[11+3*r6]*bw + sc[12+3*r6]*fw + sc[13+3*r6]*cw_s[r6][m6];
    rwn_s[r6][m6] = rn;
    rwg[b*256 + r6*64 + m6] = rn;
  }
  __syncthreads();
  if (full != nullptr) {
    const int r8 = tid>>6, w0 = (tid&63)*8;
    float a[8];
    #pragma unroll
    for (int j=0;j<8;j++) a[j]=0.f;
    for (int m3=0;m3<64;m3++){
      const float rv_ = rwn_s[r8][m3];
      const float* mr = mem + ((size_t)b*64+m3)*512 + w0;
      const float4 p0 = *(const float4*)&mr[0];
      const float4 p1 = *(const float4*)&mr[4];
      a[0]=fmaf(rv_,p0.x,a[0]); a[1]=fmaf(rv_,p0.y,a[1]);
      a[2]=fmaf(rv_,p0.z,a[2]); a[3]=fmaf(rv_,p0.w,a[3]);
      a[4]=fmaf(rv_,p1.x,a[4]); a[5]=fmaf(rv_,p1.y,a[5]);
      a[6]=fmaf(rv_,p1.z,a[6]); a[7]=fmaf(rv_,p1.w,a[7]);
    }
    u16* dst = full + ((size_t)t*32 + b)*2560 + 512 + r8*512 + w0;
    ushort4 s0, s1;
    s0.x=f2b(a[0]); s0.y=f2b(a[1]); s0.z=f2b(a[2]); s0.w=f2b(a[3]);
    s1.x=f2b(a[4]); s1.y=f2b(a[5]); s1.z=f2b(a[6]); s1.w=f2b(a[7]);
    *(ushort4*)dst = s0;
    *(ushort4*)(dst+4) = s1;
  }
  __syncthreads();
}

struct StepArgs {
  const float* emb[2];
  const int*   seq[2];
  const float* Wx0[2]; const float* Wh0[2]; const float* bx0[2]; const float* bh0[2];
  const float* Wx1[2]; const float* Wh1[2]; const float* bx1[2]; const float* bh1[2];
  const float* Wi[2];  const float* bi[2];
  float* h0[2]; float* h1[2]; float* c0; float* c1;
  float* xi2[2]; float* oc[2];
  u16* full;
  unsigned* flags; unsigned* gen;
};

// roles: lstm0 0-63, lstm1 64-127, xi 128-184, mem 185-216, idle rest
__global__ __launch_bounds__(NTHR) void k_all(StepArgs a) {
  extern __shared__ float S[];
  const int bid = blockIdx.x;
  const int role = (bid < 64) ? 0 : (bid < 128) ? 1 : (bid < 185) ? 2 : (bid < 217) ? 3 : 4;
  unsigned ep = 0;
  if (role == 3) {
    for (int i = threadIdx.x; i < L_END; i += NTHR) S[i] = 0.f;
  }
  __syncthreads();
  for (int ph = 0; ph < 2; ++ph) {
    if (role == 0)      preload_lstm(S, bid,    a.Wx0[ph], NNIN, a.Wh0[ph]);
    else if (role == 1) preload_lstm(S, bid-64, a.Wx1[ph], 512,  a.Wh1[ph]);
    else if (role == 2) preload_xi(S, bid-128, a.Wi[ph]);
    for (int i = bid*NTHR + threadIdx.x; i < 16384; i += (int)(NBLK*NTHR)) {
      stg_c(&a.h0[0][i],0.f); stg_c(&a.h0[1][i],0.f);
      stg_c(&a.h1[0][i],0.f); stg_c(&a.h1[1][i],0.f);
    }
    if (role == 0 && threadIdx.x < 256) {
      const int cid = (threadIdx.x & 31)*512 + bid*8 + (threadIdx.x >> 5);
      a.c0[cid] = 0.f;
    } else if (role == 1 && threadIdx.x < 256) {
      const int cid = (threadIdx.x & 31)*512 + (bid-64)*8 + (threadIdx.x >> 5);
      a.c1[cid] = 0.f;
    }
    gbar5(a.flags, a.gen, ++ep);
    u16* fullp = ph ? a.full : nullptr;
    for (int k = 0; k <= TT+2; ++k) {
      float* h0r = a.h0[(k+1)&1];
      float* h0w = a.h0[k&1];
      float* h1r = a.h1[k&1];
      float* h1w = a.h1[(k+1)&1];
      float* ocw = a.oc[(k+1)&1];
      float* ocr = a.oc[k&1];
      float* xiw = a.xi2[k&1];
      float* xir = a.xi2[(k+1)&1];
      if (role == 0) {
        if (k < TT)
          lstm_tile_p(S, bid, a.bx0[ph], a.bh0[ph], a.emb[ph], a.seq[ph], k,
                      nullptr, h0r, h0w, a.c0, nullptr, nullptr);
      } else if (role == 1) {
        if (k >= 1 && k <= TT)
          lstm_tile_p(S, bid-64, a.bx1[ph], a.bh1[ph], nullptr, nullptr, k-1,
                      h0r, h1r, h1w, a.c1, ocw, fullp);
      } else if (role == 2) {
        if (k >= 2 && k <= TT+1)
          xi_tile_p(S, bid-128, ocr, a.bi[ph], xiw);
      } else if (role == 3) {
        if (k >= 3)
          mem_tile_lds(S, bid-185, xir, fullp, k-3);
      }
      gbar5(a.flags, a.gen, ++ep);
    }
  }
}

// ---- standalone wrappers (fallback path, 256 thr) ----
__global__ __launch_bounds__(256) void k_lstm(
    const float* Wx, int wx_stride, const float* Wh,
    const float* bx, const float* bh,
    const float* emb, const int* seq, int t, const float* xf,
    const float* hprev, float* hcur, float* cst, float* outc, u16* full)
{
  __shared__ __align__(16) float sm[SM_FLOATS];
  lstm_tile_g(sm, blockIdx.x, Wx, wx_stride, Wh, bx, bh, emb, seq, t, xf,
              hprev, hcur, cst, outc, full);
}
__global__ __launch_bounds__(256) void k_xi(
    const float* outc, const float* Wi, const float* bi, float* xi)
{
  __shared__ __align__(16) float sm[SM_FLOATS];
  xi_tile_g(sm, blockIdx.x, outc, Wi, bi, xi);
}
__global__ __launch_bounds__(256) void k_mem(
    const float* xi, float* mem, float* link, float* prec,
    float* rwg, float* wwg, float* usg, u16* full, int t)
{
  __shared__ __align__(16) float sm[SM_FLOATS];
  mem_tile_g(sm, blockIdx.x, xi, mem, link, prec, rwg, wwg, usg, full, t);
}

// y = full @ Wo.T + bo
__global__ __launch_bounds__(256) void k_y(
    const u16* __restrict__ full,
    const float* __restrict__ Wo, const float* __restrict__ bo,
    u16* __restrict__ y)
{
  __shared__ __align__(16) float As[32][136];
  const int tid = threadIdx.x;
  const int rb = blockIdx.x >> 4, cb = blockIdx.x & 15;
  const int c = tid & 31, col = cb*32 + c;
  const int b0 = (tid>>5)*4;
  float acc0=0.f,acc1=0.f,acc2=0.f,acc3=0.f;
  for (int chunk = 0; chunk < 20; ++chunk) {
    const int k0 = chunk*128;
    for (int i = tid; i < 1024; i += 256) {
      const int r = i>>5, kk = (i&31)*4;
      const float4 v = b4f(*(const ushort4*)&full[(size_t)(rb*32+r)*2560 + k0 + kk]);
      *(float4*)&As[r][kk] = v;
    }
    __syncthreads();
    const float* Wr = Wo + (size_t)col*2560 + k0;
    #pragma unroll 8
    for (int kk = 0; kk < 128; kk += 4) {
      const float4 w4 = *(const float4*)(Wr + kk);
      const float4 a0 = *(const float4*)&As[b0+0][kk];
      const float4 a1 = *(const float4*)&As[b0+1][kk];
      const float4 a2 = *(const float4*)&As[b0+2][kk];
      const float4 a3 = *(const float4*)&As[b0+3][kk];
      acc0 = fmaf(a0.x,w4.x,fmaf(a0.y,w4.y,fmaf(a0.z,w4.z,fmaf(a0.w,w4.w,acc0))));
      acc1 = fmaf(a1.x,w4.x,fmaf(a1.y,w4.y,fmaf(a1.z,w4.z,fmaf(a1.w,w4.w,acc1))));
      acc2 = fmaf(a2.x,w4.x,fmaf(a2.y,w4.y,fmaf(a2.z,w4.z,fmaf(a2.w,w4.w,acc2))));
      acc3 = fmaf(a3.x,w4.x,fmaf(a3.y,w4.y,fmaf(a3.z,w4.z,fmaf(a3.w,w4.w,acc3))));
    }
    __syncthreads();
  }
  const float bias = bo[col];
  y[(size_t)(rb*32+b0+0)*512+col] = f2b(acc0+bias);
  y[(size_t)(rb*32+b0+1)*512+col] = f2b(acc1+bias);
  y[(size_t)(rb*32+b0+2)*512+col] = f2b(acc2+bias);
  y[(size_t)(rb*32+b0+3)*512+col] = f2b(acc3+bias);
}

// logits
__global__ __launch_bounds__(256) void k_logits(
    const u16* __restrict__ y,
    const float* __restrict__ fcW, const float* __restrict__ fcb,
    float* __restrict__ outp)
{
  __shared__ __align__(16) float As[64][68];
  const int tid = threadIdx.x;
  const int bb = blockIdx.x / 157, vt = blockIdx.x % 157;
  const int tl = tid & 15, vl = tid >> 4;
  const int t0 = tl*4;
  const int vbase = vt*64 + vl*4;
  float acc[4][4];
  #pragma unroll
  for (int i=0;i<4;i++)
    #pragma unroll
    for (int j=0;j<4;j++) acc[i][j]=0.f;
  for (int chunk = 0; chunk < 8; ++chunk) {
    const int k0 = chunk*64;
    for (int i = tid; i < 1024; i += 256) {
      const int tt = i>>4, kk = (i&15)*4;
      const float4 v = b4f(*(const ushort4*)&y[((size_t)tt*32 + bb)*512 + k0 + kk]);
      *(float4*)&As[tt][kk] = v;
    }
    __syncthreads();
    for (int kk = 0; kk < 64; kk += 4) {
      const float4 a0 = *(const float4*)&As[t0+0][kk];
      const float4 a1 = *(const float4*)&As[t0+1][kk];
      const float4 a2 = *(const float4*)&As[t0+2][kk];
      const float4 a3 = *(const float4*)&As[t0+3][kk];
      #pragma unroll
      for (int vj = 0; vj < 4; ++vj) {
        const int v = vbase + vj;
        const int vc = v < VV ? v : VV-1;
        const float4 w4 = *(const float4*)(fcW + (size_t)vc*512 + k0 + kk);
        acc[vj][0] = fmaf(a0.x,w4.x,fmaf(a0.y,w4.y,fmaf(a0.z,w4.z,fmaf(a0.w,w4.w,acc[vj][0]))));
        acc[vj][1] = fmaf(a1.x,w4.x,fmaf(a1.y,w4.y,fmaf(a1.z,w4.z,fmaf(a1.w,w4.w,acc[vj][1]))));
        acc[vj][2] = fmaf(a2.x,w4.x,fmaf(a2.y,w4.y,fmaf(a2.z,w4.z,fmaf(a2.w,w4.w,acc[vj][2]))));
        acc[vj][3] = fmaf(a3.x,w4.x,fmaf(a3.y,w4.y,fmaf(a3.z,w4.z,fmaf(a3.w,w4.w,acc[vj][3]))));
      }
    }
    __syncthreads();
  }
  #pragma unroll
  for (int vj = 0; vj < 4; ++vj) {
    const int v = vbase + vj;
    if (v < VV) {
      const float bias = fcb[v];
      float4 st;
      st.x = acc[vj][0]+bias;
      st.y = acc[vj][1]+bias;
      st.z = acc[vj][2]+bias;
      st.w = acc[vj][3]+bias;
      *(float4*)&outp[(size_t)bb*640000 + (size_t)v*64 + t0] = st;
    }
  }
}

// ---- workspace layout ----
#define O_H0A 0
#define O_H0B 16384
#define O_H1A 32768
#define O_H1B 49152
#define O_C0  65536
#define O_C1  81920
#define O_MEM 98304
#define O_FLAGS 98304
#define O_XI2   102400
#define O_OC2   217824
#define O_LINK  1146880
#define O_PREC  1277952
#define O_RW    1280000
#define O_WW    1288192
#define O_USAGE 1290240
#define STATE_FLOATS 1292288
#define O_BAR  1292288
#define O_XI   1292544
#define O_OUT  1407968
#define F32_END 1424352
#define FULL_BYTE_OFF 5697408ull
#define Y_BYTE_OFF    16183168ull
#define WS_NEED       18280320ull

extern "C" void kernel_launch(void* const* d_in, const int* in_sizes, int n_in,
                              void* d_out, int out_size, void* d_ws, size_t ws_size,
                              hipStream_t stream) {
  (void)in_sizes; (void)n_in; (void)out_size;
  if (ws_size < WS_NEED) return;
  typedef const float* cf;
  cf emb_src = (cf)d_in[0], emb_tgt = (cf)d_in[1];
  cf eW[12], dWt[12];
  for (int i=0;i<12;i++){ eW[i]=(cf)d_in[2+i]; dWt[i]=(cf)d_in[14+i]; }
  cf fcW = (cf)d_in[26], fcb = (cf)d_in[27];
  const int* inp = (const int*)d_in[28];
  const int* tgt = (const int*)d_in[29];
  float* outp = (float*)d_out;
  float* w = (float*)d_ws;

  float* h0buf[2] = { w+O_H0A, w+O_H0B };
  float* h1buf[2] = { w+O_H1A, w+O_H1B };
  float* c0 = w+O_C0;  float* c1 = w+O_C1;
  float* memb = w+O_MEM;
  float* linkb = w+O_LINK; float* precb = w+O_PREC;
  float* rwb = w+O_RW;     float* wwb = w+O_WW;   float* usageb = w+O_USAGE;
  float* xib = w+O_XI;     float* outb = w+O_OUT;
  u16* fullb = (u16*)((char*)d_ws + FULL_BYTE_OFF);
  u16* yb    = (u16*)((char*)d_ws + Y_BYTE_OFF);

  hipMemsetAsync(w, 0, (size_t)(STATE_FLOATS+256)*4, stream);

  StepArgs sa;
  sa.emb[0]=emb_src; sa.emb[1]=emb_tgt;
  sa.seq[0]=inp;     sa.seq[1]=tgt;
  sa.Wx0[0]=eW[0]; sa.Wh0[0]=eW[1]; sa.bx0[0]=eW[2]; sa.bh0[0]=eW[3];
  sa.Wx1[0]=eW[4]; sa.Wh1[0]=eW[5]; sa.bx1[0]=eW[6]; sa.bh1[0]=eW[7];
  sa.Wi[0]=eW[8];  sa.bi[0]=eW[9];
  sa.Wx0[1]=dWt[0]; sa.Wh0[1]=dWt[1]; sa.bx0[1]=dWt[2]; sa.bh0[1]=dWt[3];
  sa.Wx1[1]=dWt[4]; sa.Wh1[1]=dWt[5]; sa.bx1[1]=dWt[6]; sa.bh1[1]=dWt[7];
  sa.Wi[1]=dWt[8];  sa.bi[1]=dWt[9];
  sa.h0[0]=h0buf[0]; sa.h0[1]=h0buf[1];
  sa.h1[0]=h1buf[0]; sa.h1[1]=h1buf[1];
  sa.c0=c0; sa.c1=c1;
  sa.xi2[0]=xib;      sa.xi2[1]=w+O_XI2;
  sa.oc[0]=outb;      sa.oc[1]=w+O_OC2;
  sa.full=fullb;
  sa.flags=(unsigned*)(w + O_FLAGS);
  sa.gen=(unsigned*)(w + O_BAR);

  (void)hipFuncSetAttribute((const void*)k_all,
      hipFuncAttributeMaxDynamicSharedMemorySize, DYN_LDS_BYTES);

  void* kargs[] = { &sa };
  hipError_t err = hipLaunchCooperativeKernel((const void*)k_all, dim3(NBLK), dim3(NTHR),
                                              kargs, DYN_LDS_BYTES, stream);
  if (err != hipSuccess) {
    // fallback: per-step dispatch chain (round-4-verified path, global DNC state)
    int pp = 0;
    for (int t = 0; t < TT; ++t) {
      k_lstm<<<64,256,0,stream>>>(eW[0], NNIN, eW[1], eW[2], eW[3],
                                  emb_src, inp, t, nullptr,
                                  h0buf[pp], h0buf[pp^1], c0, nullptr, nullptr);
      k_lstm<<<64,256,0,stream>>>(eW[4], 512, eW[5], eW[6], eW[7],
                                  nullptr, nullptr, t, h0buf[pp^1],
                                  h1buf[pp], h1buf[pp^1], c1, outb, nullptr);
      k_xi<<<113,256,0,stream>>>(outb, eW[8], eW[9], xib);
      k_mem<<<32,256,0,stream>>>(xib, memb, linkb, precb, rwb, wwb, usageb,
                                 nullptr, t);
      pp ^= 1;
    }
    hipMemsetAsync(w, 0, (size_t)O_MEM*4, stream);
    pp = 0;
    for (int t = 0; t < TT; ++t) {
      k_lstm<<<64,256,0,stream>>>(dWt[0], NNIN, dWt[1], dWt[2], dWt[3],
                                  emb_tgt, tgt, t, nullptr,
                                  h0buf[pp], h0buf[pp^1], c0, nullptr, nullptr);
      k_lstm<<<64,256,0,stream>>>(dWt[4], 512, dWt[5], dWt[6], dWt[7],
                                  nullptr, nullptr, t, h0buf[pp^1],
                                  h1buf[pp], h1buf[pp^1], c1, outb, fullb);
      k_xi<<<113,256,0,stream>>>(outb, dWt[8], dWt[9], xib);
      k_mem<<<32,256,0,stream>>>(xib, memb, linkb, precb, rwb, wwb, usageb,
                                 fullb, t);
      pp ^= 1;
    }
  }

  k_y<<<1024,256,0,stream>>>(fullb, dWt[10], dWt[11], yb);
  k_logits<<<32*157,256,0,stream>>>(yb, fcW, fcb, outp);
}

// Round 18
// 4249.005 us; speedup vs baseline: 1.0069x; 1.0069x over previous
//
#include <hip/hip_runtime.h>

#define BB   32
#define DD   512
#define RR   4
#define MM   64
#define VV   10000
#define TT   64
#define IFX  3607
#define NNIN 2560
#define EPSF 1e-6f

typedef unsigned short u16;

__device__ __forceinline__ float bf(u16 u){ return __uint_as_float(((unsigned)u)<<16); }
__device__ __forceinline__ float4 b4f(ushort4 u){
  float4 f; f.x = bf(u.x); f.y = bf(u.y); f.z = bf(u.z); f.w = bf(u.w); return f;
}
__device__ __forceinline__ u16 f2b(float f){
  unsigned u = __float_as_uint(f);
  u += 0x7fffu + ((u>>16)&1u);
  return (u16)(u>>16);
}
__device__ __forceinline__ float sigmf(float x){ return 1.f/(1.f+__expf(-x)); }
__device__ __forceinline__ float softplusf(float x){ return x > 20.f ? x : log1pf(__expf(x)); }
__device__ __forceinline__ float wredSum(float v){
  #pragma unroll
  for (int s=1;s<64;s<<=1) v += __shfl_xor(v,s,64);
  return v;
}
__device__ __forceinline__ float wredMax(float v){
  #pragma unroll
  for (int s=1;s<64;s<<=1) v = fmaxf(v, __shfl_xor(v,s,64));
  return v;
}

// LLC-coherent scalar access (bypasses L2)
__device__ __forceinline__ float ldg_c(const float* p){
  return __hip_atomic_load(const_cast<float*>(p), __ATOMIC_RELAXED, __HIP_MEMORY_SCOPE_AGENT);
}
__device__ __forceinline__ void stg_c(float* p, float v){
  __hip_atomic_store(p, v, __ATOMIC_RELAXED, __HIP_MEMORY_SCOPE_AGENT);
}
__device__ __forceinline__ unsigned ldg_cu(const unsigned* p){
  return __hip_atomic_load(const_cast<unsigned*>(p), __ATOMIC_RELAXED, __HIP_MEMORY_SCOPE_AGENT);
}
__device__ __forceinline__ void stg_cu(unsigned* p, unsigned v){
  __hip_atomic_store(p, v, __ATOMIC_RELAXED, __HIP_MEMORY_SCOPE_AGENT);
}

// Batched LLC loads (issue + wait fused inside one asm: value is defined
// before any compiler-visible use -> no in-flight-register hazard)
__device__ __forceinline__ void ldg_cv4x2(const float* p0,const float* p1, float4& a,float4& b){
  asm volatile("global_load_dwordx4 %0, %2, off sc0 sc1\n\t"
               "global_load_dwordx4 %1, %3, off sc0 sc1\n\t"
               "s_waitcnt vmcnt(0)"
               : "=&v"(a),"=&v"(b)
               : "v"(p0),"v"(p1)
               : "memory");
}
__device__ __forceinline__ void ldg_c4s(const float* p0,const float* p1,const float* p2,const float* p3,
                                        float& a,float& b,float& c,float& d){
  asm volatile("global_load_dword %0, %4, off sc0 sc1\n\t"
               "global_load_dword %1, %5, off sc0 sc1\n\t"
               "global_load_dword %2, %6, off sc0 sc1\n\t"
               "global_load_dword %3, %7, off sc0 sc1\n\t"
               "s_waitcnt vmcnt(0)"
               : "=&v"(a),"=&v"(b),"=&v"(c),"=&v"(d)
               : "v"(p0),"v"(p1),"v"(p2),"v"(p3)
               : "memory");
}
__device__ __forceinline__ void ldg_c2s(const float* p0,const float* p1, float& a,float& b){
  asm volatile("global_load_dword %0, %2, off sc0 sc1\n\t"
               "global_load_dword %1, %3, off sc0 sc1\n\t"
               "s_waitcnt vmcnt(0)"
               : "=&v"(a),"=&v"(b)
               : "v"(p0),"v"(p1)
               : "memory");
}

#define SM_FLOATS 9600
#define NBLK 256u
#define NTHR 512

// ---- grid barrier v5 (512-thread blocks): flag stores, master gathers ----
__device__ __forceinline__ void gbar5(unsigned* flags, unsigned* gen, unsigned ep){
  asm volatile("s_waitcnt vmcnt(0) lgkmcnt(0)" ::: "memory");
  __syncthreads();
  if (threadIdx.x == 0) stg_cu(&flags[blockIdx.x*16], ep);
  if (blockIdx.x == 0) {
    if (threadIdx.x < 256) {
      const unsigned* f = &flags[threadIdx.x*16];
      while (ldg_cu(f) < ep) __builtin_amdgcn_s_sleep(1);
    }
    __syncthreads();
    if (threadIdx.x == 0) stg_cu(gen, ep);
  } else if (threadIdx.x == 0) {
    while (ldg_cu(gen) < ep) __builtin_amdgcn_s_sleep(1);
  }
  __syncthreads();
}

// =============== persistent-W LDS layouts ===============
#define LW_OFF 5312
#define XW_OFF 4224

__device__ __forceinline__ void preload_lstm(float* S, int tile,
    const float* __restrict__ Wx, int wx_stride, const float* __restrict__ Wh)
{
  float* WL = S + LW_OFF;
  const int tid = threadIdx.x;
  const int dblk = tile*8;
  for (int i = tid; i < 8192; i += NTHR) {
    const int r  = i >> 8;
    const int k4 = (i & 255) * 4;
    const int gr = ((r>>3)<<9) + dblk + (r&7);
    float4 v;
    if (k4 < 512) v = *(const float4*)&Wx[(size_t)gr*wx_stride + k4];
    else          v = *(const float4*)&Wh[(size_t)gr*512 + (k4-512)];
    *(float4*)&WL[r*1028 + k4] = v;
  }
}

__device__ __forceinline__ void preload_xi(float* S, int xtile, const float* __restrict__ Wi){
  float* XW = S + XW_OFF;
  const int tid = threadIdx.x;
  for (int i = tid; i < 8192; i += NTHR) {
    const int r  = i >> 7;
    const int k4 = (i & 127) * 4;
    int cr = xtile*64 + r; if (cr >= IFX) cr = IFX-1;
    *(float4*)&XW[r*516 + k4] = *(const float4*)&Wi[(size_t)cr*512 + k4];
  }
}

// ---- LSTM gates GEMM: 4 batches x 4 gates register tile, K-split-8 ----
// wave w = d-element; bg = batch group (batches bg+8i); ks = K-slice.
// Fused staging per chunk (no in-flight prefetch registers).
__device__ __noinline__ void lstm_tile_p(
    float* S, int tile,
    const float* __restrict__ bx, const float* __restrict__ bh,
    const float* emb, const int* seq, int t,
    const float* xf,
    const float* hprev, float* hcur,
    float* cst, float* outc, u16* full)
{
  float (*As)[132] = (float(*)[132])S;
  int* idxs = (int*)(S + 5280);
  const float* WL = S + LW_OFF;
  const int tid = threadIdx.x;
  const int w  = tid >> 6;          // wave = d-element 0..7
  const int bg = (tid >> 3) & 7;    // batch group
  const int ks = tid & 7;           // K-slice
  const int dblk = tile * 8;
  const int ba = tid >> 5;          // staging batch a (0..15)
  const int bbs = ba + 16;          // staging batch b (16..31)
  const int f0 = (tid & 31) * 4;    // staging f4 offset
  float acc[4][4];
  #pragma unroll
  for (int i=0;i<4;i++)
    #pragma unroll
    for (int j=0;j<4;j++) acc[i][j]=0.f;
  if (emb != nullptr && tid < 32) idxs[tid] = seq[tid*64 + t];
  __syncthreads();
  #define LSRC(ch, bb_) ( ((ch) < 4) \
      ? ((emb != nullptr) ? &emb[(size_t)idxs[bb_]*512 + (ch)*128 + f0] \
                          : &xf[(bb_)*512 + (ch)*128 + f0]) \
      : &hprev[(bb_)*512 + ((ch)*128 - 512) + f0] )
  for (int chunk = 0; chunk < 8; ++chunk) {
    {
      float4 v0, v1;
      ldg_cv4x2(LSRC(chunk,ba), LSRC(chunk,bbs), v0, v1);
      *(float4*)&As[ba][f0]  = v0;
      *(float4*)&As[bbs][f0] = v1;
    }
    __syncthreads();
    const int kb = chunk*128;
    #pragma unroll
    for (int m = 0; m < 4; ++m) {
      const int kk = ks*4 + m*32;
      float4 w4[4], a4[4];
      #pragma unroll
      for (int j=0;j<4;j++) w4[j] = *(const float4*)&WL[(w + 8*j)*1028 + kb + kk];
      #pragma unroll
      for (int i=0;i<4;i++) a4[i] = *(const float4*)&As[bg + 8*i][kk];
      #pragma unroll
      for (int i=0;i<4;i++)
        #pragma unroll
        for (int j=0;j<4;j++)
          acc[i][j] = fmaf(a4[i].x,w4[j].x, fmaf(a4[i].y,w4[j].y,
                      fmaf(a4[i].z,w4[j].z, fmaf(a4[i].w,w4[j].w, acc[i][j]))));
    }
    __syncthreads();
  }
  #undef LSRC
  // reduce over ks (8 lanes)
  #pragma unroll
  for (int i=0;i<4;i++)
    #pragma unroll
    for (int j=0;j<4;j++){
      float v = acc[i][j];
      v += __shfl_xor(v,1,64);
      v += __shfl_xor(v,2,64);
      v += __shfl_xor(v,4,64);
      acc[i][j] = v;
    }
  if (ks == 0) {
    const int d = dblk + w;
    float bias[4];
    #pragma unroll
    for (int j=0;j<4;j++){
      const int gcol = (j<<9) + d;
      bias[j] = bx[gcol] + bh[gcol];
    }
    #pragma unroll
    for (int i=0;i<4;i++){
      const int b = bg + 8*i;
      const int cid = b*512 + d;
      const float gi = acc[i][0] + bias[0];
      const float gf = acc[i][1] + bias[1];
      const float gg = acc[i][2] + bias[2];
      const float go = acc[i][3] + bias[3];
      const float cv = sigmf(gf)*cst[cid] + sigmf(gi)*tanhf(gg);
      const float hv = sigmf(go)*tanhf(cv);
      cst[cid] = cv;
      stg_c(&hcur[cid], hv);
      if (outc != nullptr) {
        const float oc = fminf(fmaxf(hv,-20.f),20.f);
        stg_c(&outc[cid], oc);
        if (full != nullptr) full[((size_t)t*32 + b)*2560 + d] = f2b(oc);
      }
    }
  }
  __syncthreads();
}

// ---- xi tile: 4 batches x 4 cols register tile, K-split-4; fused staging ----
__device__ __noinline__ void xi_tile_p(
    float* S, int xtile,
    const float* outc, const float* __restrict__ bi, float* xi)
{
  float (*As)[132] = (float(*)[132])S;
  const float* XW = S + XW_OFF;
  const int tid = threadIdx.x;
  const int w  = tid >> 6;
  const int l  = tid & 63;
  const int tt = l >> 2;            // 0..15 tiles per wave
  const int ks = l & 3;             // K-slice
  const int cg = 2*w + (tt>>3);     // 0..15
  const int bg = tt & 7;
  const int ba = tid >> 5;
  const int bbs = ba + 16;
  const int f0 = (tid & 31) * 4;
  float acc[4][4];
  #pragma unroll
  for (int i=0;i<4;i++)
    #pragma unroll
    for (int j=0;j<4;j++) acc[i][j]=0.f;
  for (int chunk = 0; chunk < 4; ++chunk) {
    {
      const int kb0 = chunk*128;
      float4 v0, v1;
      ldg_cv4x2(&outc[ba*512 + kb0 + f0], &outc[bbs*512 + kb0 + f0], v0, v1);
      *(float4*)&As[ba][f0]  = v0;
      *(float4*)&As[bbs][f0] = v1;
    }
    __syncthreads();
    const int kb = chunk*128;
    #pragma unroll
    for (int m = 0; m < 8; ++m) {
      const int kk = ks*4 + m*16;
      float4 w4[4], a4[4];
      #pragma unroll
      for (int j=0;j<4;j++) w4[j] = *(const float4*)&XW[(cg + 16*j)*516 + kb + kk];
      #pragma unroll
      for (int i=0;i<4;i++) a4[i] = *(const float4*)&As[bg + 8*i][kk];
      #pragma unroll
      for (int i=0;i<4;i++)
        #pragma unroll
        for (int j=0;j<4;j++)
          acc[i][j] = fmaf(a4[i].x,w4[j].x, fmaf(a4[i].y,w4[j].y,
                      fmaf(a4[i].z,w4[j].z, fmaf(a4[i].w,w4[j].w, acc[i][j]))));
    }
    __syncthreads();
  }
  // reduce over ks (4 lanes)
  #pragma unroll
  for (int i=0;i<4;i++)
    #pragma unroll
    for (int j=0;j<4;j++){
      float v = acc[i][j];
      v += __shfl_xor(v,1,64);
      v += __shfl_xor(v,2,64);
      acc[i][j] = v;
    }
  if (ks == 0) {
    #pragma unroll
    for (int j=0;j<4;j++){
      const int col = xtile*64 + cg + 16*j;
      if (col < IFX) {
        const float bias = bi[col];
        #pragma unroll
        for (int i=0;i<4;i++)
          stg_c(&xi[(size_t)(bg + 8*i)*IFX + col], acc[i][j] + bias);
      }
    }
  }
  __syncthreads();
}

__device__ __constant__ int kSidx[23] = {
  2048,2049,2050,2051, 2564, 3589,3590,3591,3592, 3593, 3594,
  3595,3596,3597, 3598,3599,3600, 3601,3602,3603, 3604,3605,3606
};

// ===================== LDS-persistent DNC memory step (512 thr) =====================
#define MEMPITCH 516
#define L_MEM   0
#define L_LINK  33024
#define L_RK    37184
#define L_WK    39232
#define L_RWP   39744
#define L_PREC  40000
#define L_USAGE 40064
#define L_WCW   40128
#define L_U     40192
#define L_WW    40256
#define L_CWA   40320
#define L_SC    40576
#define L_SRAW  40616
#define L_END   40640
#define DYN_LDS_BYTES 162560

__device__ __noinline__ void mem_tile_lds(
    float* S, int b, const float* xi, u16* full, int t)
{
  const int tid = threadIdx.x;
  const float* xb = xi + (size_t)b*IFX;
  float* MEMS = S + L_MEM;
  float* LNK  = S + L_LINK;
  float (*rk_s)[512] = (float(*)[512])(S + L_RK);
  float* wk_s  = S + L_WK;
  float* RWP   = S + L_RWP;
  float* PREC  = S + L_PREC;
  float* USAGE = S + L_USAGE;
  float* wcw_s = S + L_WCW;
  float* u_s   = S + L_U;
  float* WW    = S + L_WW;
  float* sorted_s = S + L_CWA;
  float* excl_s   = S + L_CWA + 64;
  int*   rank_s   = (int*)(S + L_CWA + 128);
  float (*cw_s)[64] = (float(*)[64])(S + L_CWA);
  float* sc   = S + L_SC;
  float* sraw = S + L_SRAW;

  {
    const float* base = xb + tid*4;
    float v0,v1,v2,v3;
    ldg_c4s(base+0,base+1,base+2,base+3, v0,v1,v2,v3);
    float* d = &rk_s[tid>>7][(tid&127)*4];
    d[0]=tanhf(v0); d[1]=tanhf(v1); d[2]=tanhf(v2); d[3]=tanhf(v3);
  }
  if (tid < 128) {
    const float* base = xb + 2052 + tid*4;
    float v0,v1,v2,v3;
    ldg_c4s(base+0,base+1,base+2,base+3, v0,v1,v2,v3);
    float* d = &wk_s[tid*4];
    d[0]=tanhf(v0); d[1]=tanhf(v1); d[2]=tanhf(v2); d[3]=tanhf(v3);
  }
  if (tid < 23) sraw[tid] = ldg_c(&xb[kSidx[tid]]);
  __syncthreads();
  if (tid == 0) {
    for (int r=0;r<4;r++) sc[r] = softplusf(sraw[r]);
    sc[4] = softplusf(sraw[4]);
    for (int r=0;r<4;r++) sc[5+r] = sigmf(sraw[5+r]);
    sc[9]  = sigmf(sraw[9]);
    sc[10] = sigmf(sraw[10]);
    for (int r=0;r<4;r++) {
      const float a0=sraw[11+3*r], a1=sraw[12+3*r], a2=sraw[13+3*r];
      const float mx=fmaxf(a0,fmaxf(a1,a2));
      const float e0=__expf(a0-mx), e1=__expf(a1-mx), e2=__expf(a2-mx);
      const float s=e0+e1+e2;
      sc[11+3*r]=e0/s; sc[12+3*r]=e1/s; sc[13+3*r]=e2/s;
    }
  }
  if (tid < 256) {
    const int wid = tid>>6, ln = tid&63;
    float p = 0.f;
    for (int i = ln; i < 512; i += 64) { const float v = rk_s[wid][i]; p = fmaf(v,v,p); }
    p = wredSum(p);
    if (ln == 0) sc[24+wid] = sqrtf(p);
    if (wid == 1) {
      float q2 = 0.f;
      for (int i = ln; i < 512; i += 64) { const float v = wk_s[i]; q2 = fmaf(v,v,q2); }
      q2 = wredSum(q2);
      if (ln == 0) sc[23] = sqrtf(q2);
    }
  }
  __syncthreads();
  if (tid < 256) {
    const int m = tid>>2, q = tid&3;
    const float* mr = MEMS + m*MEMPITCH;
    float d = 0.f, ss = 0.f;
    for (int i = q*128; i < q*128+128; i += 4) {
      const float4 mv = *(const float4*)&mr[i];
      d = fmaf(mv.x, wk_s[i  ], d); d = fmaf(mv.y, wk_s[i+1], d);
      d = fmaf(mv.z, wk_s[i+2], d); d = fmaf(mv.w, wk_s[i+3], d);
      ss = fmaf(mv.x,mv.x,ss); ss = fmaf(mv.y,mv.y,ss);
      ss = fmaf(mv.z,mv.z,ss); ss = fmaf(mv.w,mv.w,ss);
    }
    d  += __shfl_xor(d,1,64);  d  += __shfl_xor(d,2,64);
    ss += __shfl_xor(ss,1,64); ss += __shfl_xor(ss,2,64);
    if (q == 0) wcw_s[m] = d / ((sqrtf(ss)+EPSF)*(sc[23]+EPSF)) * sc[4];
  }
  if (tid < 64) {
    const float uo = USAGE[tid];
    float u = uo + (1.f-uo)*WW[tid];
    #pragma unroll
    for (int r=0;r<4;r++) u *= (1.f - sc[5+r]*RWP[r*64+tid]);
    USAGE[tid] = u;
  }
  __syncthreads();
  if (tid < 64) {
    const float v = wcw_s[tid];
    const float mx = wredMax(v);
    const float e = __expf(v-mx);
    const float s2 = wredSum(e);
    wcw_s[tid] = e/s2;
    u_s[tid] = EPSF + (1.f-EPSF)*USAGE[tid];
  }
  __syncthreads();
  if (tid < 64) {
    const float u = u_s[tid]; int rk2 = 0;
    for (int j=0;j<64;j++){ const float uj = u_s[j]; rk2 += (uj<u) || (uj==u && j<tid); }
    rank_s[tid] = rk2; sorted_s[rk2] = u;
  }
  __syncthreads();
  if (tid == 0) { float run = 1.f; for (int p2=0;p2<64;p2++){ excl_s[p2]=run; run*=sorted_s[p2]; } }
  __syncthreads();
  if (tid < 64) {
    const float al = (1.f - u_s[tid]) * excl_s[rank_s[tid]];
    const float wwv = sc[10]*(sc[9]*al + (1.f-sc[9])*wcw_s[tid]);
    WW[tid] = wwv;
    const float s3 = wredSum(wwv);
    if (tid==0) sc[28] = s3;
  }
  __syncthreads();
  {
    float e0,w0;
    ldg_c2s(&xb[2565+tid], &xb[3077+tid], e0, w0);
    const float er0 = sigmf(e0);
    const float wv0 = tanhf(w0);
    #pragma unroll 4
    for (int m=0;m<64;m++){
      const float wwm = WW[m];
      float* p = MEMS + m*MEMPITCH + tid;
      p[0] = p[0]*(1.f - wwm*er0) + wwm*wv0;
    }
  }
  __syncthreads();
  for (int e = tid; e < 4096; e += NTHR) {
    const int i2 = e>>6, j2 = e&63;
    const float lv = LNK[i2*65+j2];
    LNK[i2*65+j2] = (i2==j2) ? 0.f
               : ((1.f - WW[i2] - WW[j2])*lv + WW[i2]*PREC[j2]);
  }
  __syncthreads();
  if (tid < 64) PREC[tid] = (1.f - sc[28])*PREC[tid] + WW[tid];
  __syncthreads();
  const int r6 = tid>>6, m6 = tid&63;
  if (tid < 256) {
    const float* mr = MEMS + m6*MEMPITCH;
    const float* rkr = rk_s[r6];
    float d = 0.f, ss = 0.f;
    for (int i=0;i<512;i+=4){
      const float4 mv = *(const float4*)&mr[i];
      d = fmaf(mv.x, rkr[i  ], d); d = fmaf(mv.y, rkr[i+1], d);
      d = fmaf(mv.z, rkr[i+2], d); d = fmaf(mv.w, rkr[i+3], d);
      ss = fmaf(mv.x,mv.x,ss); ss = fmaf(mv.y,mv.y,ss);
      ss = fmaf(mv.z,mv.z,ss); ss = fmaf(mv.w,mv.w,ss);
    }
    const float cv = d / ((sqrtf(ss)+EPSF)*(sc[24+r6]+EPSF)) * sc[r6];
    const float mx = wredMax(cv);
    const float e = __expf(cv-mx);
    const float s2 = wredSum(e);
    cw_s[r6][m6] = e/s2;
  }
  __syncthreads();
  float rn = 0.f;
  if (tid < 256) {
    float fw = 0.f, bw = 0.f;
    #pragma unroll 8
    for (int m3=0;m3<64;m3++){
      const float rp = RWP[r6*64+m3];
      fw = fmaf(LNK[m6*65+m3], rp, fw);
      bw = fmaf(LNK[m3*65+m6], rp, bw);
    }
    rn = sc[11+3*r6]*bw + sc[12+3*r6]*fw + sc[13+3*r6]*cw_s[r6][m6];
  }
  __syncthreads();
  if (tid < 256) RWP[r6*64+m6] = rn;
  __syncthreads();
  if (full != nullptr && tid < 256) {
    const int l = tid&63, r8 = tid>>6;
    float a[8];
    #pragma unroll
    for (int j=0;j<8;j++) a[j]=0.f;
    for (int m3=0;m3<64;m3++){
      const float rv_ = RWP[r8*64+m3];
      const float* mr = MEMS + m3*MEMPITCH + 2*l;
      #pragma unroll
      for (int j=0;j<4;j++){
        const float2 v = *(const float2*)&mr[128*j];
        a[2*j]   = fmaf(rv_, v.x, a[2*j]);
        a[2*j+1] = fmaf(rv_, v.y, a[2*j+1]);
      }
    }
    u16* dst = full + ((size_t)t*32 + b)*2560 + 512 + r8*512;
    #pragma unroll
    for (int j=0;j<4;j++){
      const unsigned wd = (unsigned)f2b(a[2*j]) | ((unsigned)f2b(a[2*j+1])<<16);
      *(unsigned*)&dst[2*l + 128*j] = wd;
    }
  }
  __syncthreads();
}

// ======= fallback-path tiles (round-4-verified, 256 thr, global W) =======
__device__ __noinline__ void lstm_tile_g(
    float* sm, int tile,
    const float* __restrict__ Wx, int wx_stride,
    const float* __restrict__ Wh,
    const float* __restrict__ bx, const float* __restrict__ bh,
    const float* emb, const int* seq, int t,
    const float* xf,
    const float* hprev, float* hcur,
    float* cst, float* outc, u16* full)
{
  float (*As)[132] = (float(*)[132])sm;
  float (*Ws)[132] = (float(*)[132])(sm + 4224);
  float* gs = sm + 8448;
  int* idxs = (int*)(sm + 9504);
  const int tid = threadIdx.x;
  const int c = tid & 31;
  const int dblk = tile * 8;
  const int gcol = ((c>>3)<<9) + dblk + (c&7);
  const int b0 = (tid >> 5) * 4;
  float acc0=0.f, acc1=0.f, acc2=0.f, acc3=0.f;
  if (emb != nullptr && tid < 32) idxs[tid] = seq[tid*64 + t];
  __syncthreads();
  for (int chunk = 0; chunk < 8; ++chunk) {
    const int k0 = chunk * 128;
    const bool xp = (chunk < 4);
    for (int i = tid; i < 1024; i += 256) {
      const int bb2 = i >> 5, f4i = (i & 31)*4;
      if (xp && emb != nullptr) {
        *(float4*)&As[bb2][f4i] = *(const float4*)&emb[(size_t)idxs[bb2]*512 + k0 + f4i];
      } else {
        const float* src = xp ? &xf[bb2*512 + k0 + f4i]
                              : &hprev[bb2*512 + (k0-512) + f4i];
        As[bb2][f4i+0] = ldg_c(src+0);
        As[bb2][f4i+1] = ldg_c(src+1);
        As[bb2][f4i+2] = ldg_c(src+2);
        As[bb2][f4i+3] = ldg_c(src+3);
      }
    }
    for (int i = tid; i < 1024; i += 256) {
      const int r = i >> 5, f4i = (i & 31)*4;
      const int gr = ((r>>3)<<9) + dblk + (r&7);
      const float4 v = xp ? *(const float4*)&Wx[(size_t)gr*wx_stride + k0 + f4i]
                          : *(const float4*)&Wh[(size_t)gr*512 + (k0-512) + f4i];
      *(float4*)&Ws[r][f4i] = v;
    }
    __syncthreads();
    #pragma unroll 8
    for (int kk = 0; kk < 128; kk += 4) {
      const float4 w4 = *(const float4*)&Ws[c][kk];
      const float4 a0 = *(const float4*)&As[b0+0][kk];
      const float4 a1 = *(const float4*)&As[b0+1][kk];
      const float4 a2 = *(const float4*)&As[b0+2][kk];
      const float4 a3 = *(const float4*)&As[b0+3][kk];
      acc0 = fmaf(a0.x,w4.x,fmaf(a0.y,w4.y,fmaf(a0.z,w4.z,fmaf(a0.w,w4.w,acc0))));
      acc1 = fmaf(a1.x,w4.x,fmaf(a1.y,w4.y,fmaf(a1.z,w4.z,fmaf(a1.w,w4.w,acc1))));
      acc2 = fmaf(a2.x,w4.x,fmaf(a2.y,w4.y,fmaf(a2.z,w4.z,fmaf(a2.w,w4.w,acc2))));
      acc3 = fmaf(a3.x,w4.x,fmaf(a3.y,w4.y,fmaf(a3.z,w4.z,fmaf(a3.w,w4.w,acc3))));
    }
    __syncthreads();
  }
  const float bias = bx[gcol] + bh[gcol];
  gs[c*33 + b0+0] = acc0 + bias;
  gs[c*33 + b0+1] = acc1 + bias;
  gs[c*33 + b0+2] = acc2 + bias;
  gs[c*33 + b0+3] = acc3 + bias;
  __syncthreads();
  {
    const int b2 = tid & 31, dl2 = tid >> 5;
    const float gi = gs[(0*8+dl2)*33 + b2];
    const float gf = gs[(1*8+dl2)*33 + b2];
    const float gg = gs[(2*8+dl2)*33 + b2];
    const float go = gs[(3*8+dl2)*33 + b2];
    const int d = dblk + dl2;
    const int cid = b2*512 + d;
    const float cv = sigmf(gf)*cst[cid] + sigmf(gi)*tanhf(gg);
    const float hv = sigmf(go)*tanhf(cv);
    cst[cid] = cv;
    stg_c(&hcur[cid], hv);
    if (outc != nullptr) {
      const float oc = fminf(fmaxf(hv,-20.f),20.f);
      stg_c(&outc[cid], oc);
      if (full != nullptr) full[((size_t)t*32 + b2)*2560 + d] = f2b(oc);
    }
  }
  __syncthreads();
}

__device__ __noinline__ void xi_tile_g(
    float* sm, int tile,
    const float* outc,
    const float* __restrict__ Wi, const float* __restrict__ bi,
    float* xi)
{
  float (*As)[132] = (float(*)[132])sm;
  float (*Ws)[132] = (float(*)[132])(sm + 4224);
  const int tid = threadIdx.x;
  const int c = tid & 31;
  const int col = tile*32 + c;
  const int b0 = (tid>>5)*4;
  float acc0=0.f,acc1=0.f,acc2=0.f,acc3=0.f;
  for (int chunk = 0; chunk < 4; ++chunk) {
    const int k0 = chunk*128;
    for (int i = tid; i < 1024; i += 256) {
      const int bb2 = i>>5, f4i = (i&31)*4;
      const float* src = &outc[bb2*512 + k0 + f4i];
      As[bb2][f4i+0] = ldg_c(src+0);
      As[bb2][f4i+1] = ldg_c(src+1);
      As[bb2][f4i+2] = ldg_c(src+2);
      As[bb2][f4i+3] = ldg_c(src+3);
    }
    for (int i = tid; i < 1024; i += 256) {
      const int r = i>>5, f4i = (i&31)*4;
      int cr = tile*32 + r; cr = cr < IFX ? cr : IFX-1;
      *(float4*)&Ws[r][f4i] = *(const float4*)&Wi[(size_t)cr*512 + k0 + f4i];
    }
    __syncthreads();
    #pragma unroll 8
    for (int kk = 0; kk < 128; kk += 4) {
      const float4 w4 = *(const float4*)&Ws[c][kk];
      const float4 a0 = *(const float4*)&As[b0+0][kk];
      const float4 a1 = *(const float4*)&As[b0+1][kk];
      const float4 a2 = *(const float4*)&As[b0+2][kk];
      const float4 a3 = *(const float4*)&As[b0+3][kk];
      acc0 = fmaf(a0.x,w4.x,fmaf(a0.y,w4.y,fmaf(a0.z,w4.z,fmaf(a0.w,w4.w,acc0))));
      acc1 = fmaf(a1.x,w4.x,fmaf(a1.y,w4.y,fmaf(a1.z,w4.z,fmaf(a1.w,w4.w,acc1))));
      acc2 = fmaf(a2.x,w4.x,fmaf(a2.y,w4.y,fmaf(a2.z,w4.z,fmaf(a2.w,w4.w,acc2))));
      acc3 = fmaf(a3.x,w4.x,fmaf(a3.y,w4.y,fmaf(a3.z,w4.z,fmaf(a3.w,w4.w,acc3))));
    }
    __syncthreads();
  }
  if (col < IFX) {
    const float bias = bi[col];
    stg_c(&xi[(size_t)(b0+0)*IFX + col], acc0 + bias);
    stg_c(&xi[(size_t)(b0+1)*IFX + col], acc1 + bias);
    stg_c(&xi[(size_t)(b0+2)*IFX + col], acc2 + bias);
    stg_c(&xi[(size_t)(b0+3)*IFX + col], acc3 + bias);
  }
  __syncthreads();
}

__device__ __noinline__ void mem_tile_g(
    float* sm, int b,
    const float* xi,
    float* mem,
    float* link, float* prec,
    float* rwg, float* wwg, float* usg,
    u16* full, int t)
{
  const int tid = threadIdx.x;
  const float* xb = xi + (size_t)b*IFX;
  float (*rk_s)[512]  = (float(*)[512])sm;
  float* wk_s   = sm + 2048;
  float* er_s   = sm + 2560;
  float* wv_s   = sm + 3072;
  float (*rwp_s)[64]  = (float(*)[64])(sm + 3584);
  float* prec_s = sm + 3840;
  float* usage_s= sm + 3904;
  float* wcw_s  = sm + 3968;
  float* u_s    = sm + 4032;
  float* ww_s   = sm + 4096;
  float* sorted_s = sm + 4160;
  float* excl_s = sm + 4224;
  int*   rank_s = (int*)(sm + 4288);
  float (*cw_s)[64]  = (float(*)[64])(sm + 4352);
  float (*rwn_s)[64] = (float(*)[64])(sm + 4608);
  float* mn_s   = sm + 4864;
  float* sc     = sm + 4928;
  float (*link_s)[65] = (float(*)[65])(sm + 4976);

  for (int i = tid; i < 2048; i += 256) rk_s[i>>9][i&511] = tanhf(ldg_c(&xb[i]));
  for (int i = tid; i < 512; i += 256) {
    wk_s[i] = tanhf(ldg_c(&xb[2052+i]));
    er_s[i] = sigmf(ldg_c(&xb[2565+i]));
    wv_s[i] = tanhf(ldg_c(&xb[3077+i]));
  }
  rwp_s[tid>>6][tid&63] = rwg[b*256 + tid];
  if (tid < 64) { prec_s[tid] = prec[b*64+tid]; usage_s[tid] = usg[b*64+tid]; }
  if (tid == 0) {
    for (int r=0;r<4;r++) sc[r] = softplusf(ldg_c(&xb[2048+r]));
    sc[4] = softplusf(ldg_c(&xb[2564]));
    for (int r=0;r<4;r++) sc[5+r] = sigmf(ldg_c(&xb[3589+r]));
    sc[9]  = sigmf(ldg_c(&xb[3593]));
    sc[10] = sigmf(ldg_c(&xb[3594]));
    for (int r=0;r<4;r++) {
      const float a0=ldg_c(&xb[3595+3*r]), a1=ldg_c(&xb[3596+3*r]), a2=ldg_c(&xb[3597+3*r]);
      const float mx=fmaxf(a0,fmaxf(a1,a2));
      const float e0=__expf(a0-mx), e1=__expf(a1-mx), e2=__expf(a2-mx);
      const float s=e0+e1+e2;
      sc[11+3*r]=e0/s; sc[12+3*r]=e1/s; sc[13+3*r]=e2/s;
    }
  }
  __syncthreads();
  {
    const int wid = tid>>6, ln = tid&63;
    float p = 0.f;
    for (int i = ln; i < 512; i += 64) { const float v = rk_s[wid][i]; p = fmaf(v,v,p); }
    p = wredSum(p);
    if (ln == 0) sc[24+wid] = sqrtf(p);
    if (wid == 1) {
      float q2 = 0.f;
      for (int i = ln; i < 512; i += 64) { const float v = wk_s[i]; q2 = fmaf(v,v,q2); }
      q2 = wredSum(q2);
      if (ln == 0) sc[23] = sqrtf(q2);
    }
  }
  __syncthreads();
  {
    const int m = tid>>2, q = tid&3;
    const float* mr = mem + ((size_t)b*64 + m)*512;
    float d = 0.f, ss = 0.f;
    for (int i = q*128; i < q*128+128; i += 4) {
      const float4 mv = *(const float4*)&mr[i];
      d = fmaf(mv.x, wk_s[i  ], d); d = fmaf(mv.y, wk_s[i+1], d);
      d = fmaf(mv.z, wk_s[i+2], d); d = fmaf(mv.w, wk_s[i+3], d);
      ss = fmaf(mv.x,mv.x,ss); ss = fmaf(mv.y,mv.y,ss);
      ss = fmaf(mv.z,mv.z,ss); ss = fmaf(mv.w,mv.w,ss);
    }
    d  += __shfl_xor(d,1,64);  d  += __shfl_xor(d,2,64);
    ss += __shfl_xor(ss,1,64); ss += __shfl_xor(ss,2,64);
    if (q == 0) wcw_s[m] = d / ((sqrtf(ss)+EPSF)*(sc[23]+EPSF)) * sc[4];
  }
  if (tid < 64) {
    const float uo = usage_s[tid];
    const float wwp = wwg[b*64+tid];
    float u = uo + (1.f-uo)*wwp;
    #pragma unroll
    for (int r=0;r<4;r++) u *= (1.f - sc[5+r]*rwp_s[r][tid]);
    usage_s[tid] = u; usg[b*64+tid] = u;
  }
  __syncthreads();
  if (tid < 64) {
    const float v = wcw_s[tid];
    const float mx = wredMax(v);
    const float e = __expf(v-mx);
    const float s2 = wredSum(e);
    wcw_s[tid] = e/s2;
    u_s[tid] = EPSF + (1.f-EPSF)*usage_s[tid];
  }
  __syncthreads();
  if (tid < 64) {
    const float u = u_s[tid]; int rk2 = 0;
    for (int j=0;j<64;j++){ const float uj = u_s[j]; rk2 += (uj<u) || (uj==u && j<tid); }
    rank_s[tid] = rk2; sorted_s[rk2] = u;
  }
  __syncthreads();
  if (tid == 0) { float run = 1.f; for (int p2=0;p2<64;p2++){ excl_s[p2]=run; run*=sorted_s[p2]; } }
  __syncthreads();
  if (tid < 64) {
    const float al = (1.f - u_s[tid]) * excl_s[rank_s[tid]];
    const float wwv = sc[10]*(sc[9]*al + (1.f-sc[9])*wcw_s[tid]);
    ww_s[tid] = wwv; wwg[b*64+tid] = wwv;
    const float s3 = wredSum(wwv);
    if (tid==0) sc[28] = s3;
  }
  __syncthreads();
  {
    const int m = tid>>2, q = tid&3;
    const float wwm = ww_s[m];
    float* mr = mem + ((size_t)b*64 + m)*512;
    float ss = 0.f;
    for (int i = q*128; i < q*128+128; i += 4) {
      float4 mv = *(const float4*)&mr[i];
      mv.x = mv.x*(1.f - wwm*er_s[i  ]) + wwm*wv_s[i  ];
      mv.y = mv.y*(1.f - wwm*er_s[i+1]) + wwm*wv_s[i+1];
      mv.z = mv.z*(1.f - wwm*er_s[i+2]) + wwm*wv_s[i+2];
      mv.w = mv.w*(1.f - wwm*er_s[i+3]) + wwm*wv_s[i+3];
      *(float4*)&mr[i] = mv;
      ss += mv.x*mv.x + mv.y*mv.y + mv.z*mv.z + mv.w*mv.w;
    }
    ss += __shfl_xor(ss,1,64); ss += __shfl_xor(ss,2,64);
    if (q==0) mn_s[m] = sqrtf(ss);
  }
  __syncthreads();
  {
    float* lrow = link + (size_t)b*4096;
    for (int e = tid; e < 4096; e += 256) {
      const int i2 = e>>6, j2 = e&63;
      const float ln2 = (i2==j2) ? 0.f
                 : ((1.f - ww_s[i2] - ww_s[j2])*lrow[e] + ww_s[i2]*prec_s[j2]);
      link_s[i2][j2] = ln2;
      lrow[e] = ln2;
    }
  }
  if (tid < 64) prec[b*64+tid] = (1.f - sc[28])*prec_s[tid] + ww_s[tid];
  __syncthreads();
  const int r6 = tid>>6, m6 = tid&63;
  {
    const float* mr = mem + ((size_t)b*64 + m6)*512;
    const float* rkr = rk_s[r6];
    float d = 0.f;
    for (int i=0;i<512;i+=4){
      const float4 mv = *(const float4*)&mr[i];
      d = fmaf(mv.x, rkr[i  ], d); d = fmaf(mv.y, rkr[i+1], d);
      d = fmaf(mv.z, rkr[i+2], d); d = fmaf(mv.w, rkr[i+3], d);
    }
    const float cv = d / ((mn_s[m6]+EPSF)*(sc[24+r6]+EPSF)) * sc[r6];
    const float mx = wredMax(cv);
    const float e = __expf(cv-mx);
    const float s2 = wredSum(e);
    cw_s[r6][m6] = e/s2;
  }
  __syncthreads();
  {
    float fw = 0.f, bw = 0.f;
    #pragma unroll 8
    for (int m3=0;m3<64;m3++){
      const float rp = rwp_s[r6][m3];
      fw = fmaf(link_s[m6][m3], rp, fw);
      bw = fmaf(link_s[m3][m6], rp, bw);
    }
    const float rn = sc[11+3*r6]*bw + sc[12+3*r6]*fw + sc[13+3*r6]*cw_s[r6][m6];
    rwn_s[r6][m6] = rn;
    rwg[b*256 + r6*64 + m6] = rn;
  }
  __syncthreads();
  if (full != nullptr) {
    const int r8 = tid>>6, w0 = (tid&63)*8;
    float a[8];
    #pragma unroll
    for (int j=0;j<8;j++) a[j]=0.f;
    for (int m3=0;m3<64;m3++){
      const float rv_ = rwn_s[r8][m3];
      const float* mr = mem + ((size_t)b*64+m3)*512 + w0;
      const float4 p0 = *(const float4*)&mr[0];
      const float4 p1 = *(const float4*)&mr[4];
      a[0]=fmaf(rv_,p0.x,a[0]); a[1]=fmaf(rv_,p0.y,a[1]);
      a[2]=fmaf(rv_,p0.z,a[2]); a[3]=fmaf(rv_,p0.w,a[3]);
      a[4]=fmaf(rv_,p1.x,a[4]); a[5]=fmaf(rv_,p1.y,a[5]);
      a[6]=fmaf(rv_,p1.z,a[6]); a[7]=fmaf(rv_,p1.w,a[7]);
    }
    u16* dst = full + ((size_t)t*32 + b)*2560 + 512 + r8*512 + w0;
    ushort4 s0, s1;
    s0.x=f2b(a[0]); s0.y=f2b(a[1]); s0.z=f2b(a[2]); s0.w=f2b(a[3]);
    s1.x=f2b(a[4]); s1.y=f2b(a[5]); s1.z=f2b(a[6]); s1.w=f2b(a[7]);
    *(ushort4*)dst = s0;
    *(ushort4*)(dst+4) = s1;
  }
  __syncthreads();
}

struct StepArgs {
  const float* emb[2];
  const int*   seq[2];
  const float* Wx0[2]; const float* Wh0[2]; const float* bx0[2]; const float* bh0[2];
  const float* Wx1[2]; const float* Wh1[2]; const float* bx1[2]; const float* bh1[2];
  const float* Wi[2];  const float* bi[2];
  float* h0[2]; float* h1[2]; float* c0; float* c1;
  float* xi2[2]; float* oc[2];
  u16* full;
  unsigned* flags; unsigned* gen;
};

// roles: lstm0 0-63, lstm1 64-127, xi 128-184, mem 185-216, idle rest
__global__ __launch_bounds__(NTHR) void k_all(StepArgs a) {
  extern __shared__ float S[];
  const int bid = blockIdx.x;
  const int role = (bid < 64) ? 0 : (bid < 128) ? 1 : (bid < 185) ? 2 : (bid < 217) ? 3 : 4;
  unsigned ep = 0;
  if (role == 3) {
    for (int i = threadIdx.x; i < L_END; i += NTHR) S[i] = 0.f;
  }
  __syncthreads();
  for (int ph = 0; ph < 2; ++ph) {
    if (role == 0)      preload_lstm(S, bid,    a.Wx0[ph], NNIN, a.Wh0[ph]);
    else if (role == 1) preload_lstm(S, bid-64, a.Wx1[ph], 512,  a.Wh1[ph]);
    else if (role == 2) preload_xi(S, bid-128, a.Wi[ph]);
    for (int i = bid*NTHR + threadIdx.x; i < 16384; i += (int)(NBLK*NTHR)) {
      stg_c(&a.h0[0][i],0.f); stg_c(&a.h0[1][i],0.f);
      stg_c(&a.h1[0][i],0.f); stg_c(&a.h1[1][i],0.f);
    }
    if (role == 0 && threadIdx.x < 256) {
      const int cid = (threadIdx.x & 31)*512 + bid*8 + (threadIdx.x >> 5);
      a.c0[cid] = 0.f;
    } else if (role == 1 && threadIdx.x < 256) {
      const int cid = (threadIdx.x & 31)*512 + (bid-64)*8 + (threadIdx.x >> 5);
      a.c1[cid] = 0.f;
    }
    gbar5(a.flags, a.gen, ++ep);
    u16* fullp = ph ? a.full : nullptr;
    for (int k = 0; k <= TT+2; ++k) {
      float* h0r = a.h0[(k+1)&1];
      float* h0w = a.h0[k&1];
      float* h1r = a.h1[k&1];
      float* h1w = a.h1[(k+1)&1];
      float* ocw = a.oc[(k+1)&1];
      float* ocr = a.oc[k&1];
      float* xiw = a.xi2[k&1];
      float* xir = a.xi2[(k+1)&1];
      if (role == 0) {
        if (k < TT)
          lstm_tile_p(S, bid, a.bx0[ph], a.bh0[ph], a.emb[ph], a.seq[ph], k,
                      nullptr, h0r, h0w, a.c0, nullptr, nullptr);
      } else if (role == 1) {
        if (k >= 1 && k <= TT)
          lstm_tile_p(S, bid-64, a.bx1[ph], a.bh1[ph], nullptr, nullptr, k-1,
                      h0r, h1r, h1w, a.c1, ocw, fullp);
      } else if (role == 2) {
        if (k >= 2 && k <= TT+1)
          xi_tile_p(S, bid-128, ocr, a.bi[ph], xiw);
      } else if (role == 3) {
        if (k >= 3)
          mem_tile_lds(S, bid-185, xir, fullp, k-3);
      }
      gbar5(a.flags, a.gen, ++ep);
    }
  }
}

// ---- standalone wrappers (fallback path, 256 thr) ----
__global__ __launch_bounds__(256) void k_lstm(
    const float* Wx, int wx_stride, const float* Wh,
    const float* bx, const float* bh,
    const float* emb, const int* seq, int t, const float* xf,
    const float* hprev, float* hcur, float* cst, float* outc, u16* full)
{
  __shared__ __align__(16) float sm[SM_FLOATS];
  lstm_tile_g(sm, blockIdx.x, Wx, wx_stride, Wh, bx, bh, emb, seq, t, xf,
              hprev, hcur, cst, outc, full);
}
__global__ __launch_bounds__(256) void k_xi(
    const float* outc, const float* Wi, const float* bi, float* xi)
{
  __shared__ __align__(16) float sm[SM_FLOATS];
  xi_tile_g(sm, blockIdx.x, outc, Wi, bi, xi);
}
__global__ __launch_bounds__(256) void k_mem(
    const float* xi, float* mem, float* link, float* prec,
    float* rwg, float* wwg, float* usg, u16* full, int t)
{
  __shared__ __align__(16) float sm[SM_FLOATS];
  mem_tile_g(sm, blockIdx.x, xi, mem, link, prec, rwg, wwg, usg, full, t);
}

// y = full @ Wo.T + bo
__global__ __launch_bounds__(256) void k_y(
    const u16* __restrict__ full,
    const float* __restrict__ Wo, const float* __restrict__ bo,
    u16* __restrict__ y)
{
  __shared__ __align__(16) float As[32][136];
  const int tid = threadIdx.x;
  const int rb = blockIdx.x >> 4, cb = blockIdx.x & 15;
  const int c = tid & 31, col = cb*32 + c;
  const int b0 = (tid>>5)*4;
  float acc0=0.f,acc1=0.f,acc2=0.f,acc3=0.f;
  for (int chunk = 0; chunk < 20; ++chunk) {
    const int k0 = chunk*128;
    for (int i = tid; i < 1024; i += 256) {
      const int r = i>>5, kk = (i&31)*4;
      const float4 v = b4f(*(const ushort4*)&full[(size_t)(rb*32+r)*2560 + k0 + kk]);
      *(float4*)&As[r][kk] = v;
    }
    __syncthreads();
    const float* Wr = Wo + (size_t)col*2560 + k0;
    #pragma unroll 8
    for (int kk = 0; kk < 128; kk += 4) {
      const float4 w4 = *(const float4*)(Wr + kk);
      const float4 a0 = *(const float4*)&As[b0+0][kk];
      const float4 a1 = *(const float4*)&As[b0+1][kk];
      const float4 a2 = *(const float4*)&As[b0+2][kk];
      const float4 a3 = *(const float4*)&As[b0+3][kk];
      acc0 = fmaf(a0.x,w4.x,fmaf(a0.y,w4.y,fmaf(a0.z,w4.z,fmaf(a0.w,w4.w,acc0))));
      acc1 = fmaf(a1.x,w4.x,fmaf(a1.y,w4.y,fmaf(a1.z,w4.z,fmaf(a1.w,w4.w,acc1))));
      acc2 = fmaf(a2.x,w4.x,fmaf(a2.y,w4.y,fmaf(a2.z,w4.z,fmaf(a2.w,w4.w,acc2))));
      acc3 = fmaf(a3.x,w4.x,fmaf(a3.y,w4.y,fmaf(a3.z,w4.z,fmaf(a3.w,w4.w,acc3))));
    }
    __syncthreads();
  }
  const float bias = bo[col];
  y[(size_t)(rb*32+b0+0)*512+col] = f2b(acc0+bias);
  y[(size_t)(rb*32+b0+1)*512+col] = f2b(acc1+bias);
  y[(size_t)(rb*32+b0+2)*512+col] = f2b(acc2+bias);
  y[(size_t)(rb*32+b0+3)*512+col] = f2b(acc3+bias);
}

// logits
__global__ __launch_bounds__(256) void k_logits(
    const u16* __restrict__ y,
    const float* __restrict__ fcW, const float* __restrict__ fcb,
    float* __restrict__ outp)
{
  __shared__ __align__(16) float As[64][68];
  const int tid = threadIdx.x;
  const int bb = blockIdx.x / 157, vt = blockIdx.x % 157;
  const int tl = tid & 15, vl = tid >> 4;
  const int t0 = tl*4;
  const int vbase = vt*64 + vl*4;
  float acc[4][4];
  #pragma unroll
  for (int i=0;i<4;i++)
    #pragma unroll
    for (int j=0;j<4;j++) acc[i][j]=0.f;
  for (int chunk = 0; chunk < 8; ++chunk) {
    const int k0 = chunk*64;
    for (int i = tid; i < 1024; i += 256) {
      const int tt = i>>4, kk = (i&15)*4;
      const float4 v = b4f(*(const ushort4*)&y[((size_t)tt*32 + bb)*512 + k0 + kk]);
      *(float4*)&As[tt][kk] = v;
    }
    __syncthreads();
    for (int kk = 0; kk < 64; kk += 4) {
      const float4 a0 = *(const float4*)&As[t0+0][kk];
      const float4 a1 = *(const float4*)&As[t0+1][kk];
      const float4 a2 = *(const float4*)&As[t0+2][kk];
      const float4 a3 = *(const float4*)&As[t0+3][kk];
      #pragma unroll
      for (int vj = 0; vj < 4; ++vj) {
        const int v = vbase + vj;
        const int vc = v < VV ? v : VV-1;
        const float4 w4 = *(const float4*)(fcW + (size_t)vc*512 + k0 + kk);
        acc[vj][0] = fmaf(a0.x,w4.x,fmaf(a0.y,w4.y,fmaf(a0.z,w4.z,fmaf(a0.w,w4.w,acc[vj][0]))));
        acc[vj][1] = fmaf(a1.x,w4.x,fmaf(a1.y,w4.y,fmaf(a1.z,w4.z,fmaf(a1.w,w4.w,acc[vj][1]))));
        acc[vj][2] = fmaf(a2.x,w4.x,fmaf(a2.y,w4.y,fmaf(a2.z,w4.z,fmaf(a2.w,w4.w,acc[vj][2]))));
        acc[vj][3] = fmaf(a3.x,w4.x,fmaf(a3.y,w4.y,fmaf(a3.z,w4.z,fmaf(a3.w,w4.w,acc[vj][3]))));
      }
    }
    __syncthreads();
  }
  #pragma unroll
  for (int vj = 0; vj < 4; ++vj) {
    const int v = vbase + vj;
    if (v < VV) {
      const float bias = fcb[v];
      float4 st;
      st.x = acc[vj][0]+bias;
      st.y = acc[vj][1]+bias;
      st.z = acc[vj][2]+bias;
      st.w = acc[vj][3]+bias;
      *(float4*)&outp[(size_t)bb*640000 + (size_t)v*64 + t0] = st;
    }
  }
}

// ---- workspace layout ----
#define O_H0A 0
#define O_H0B 16384
#define O_H1A 32768
#define O_H1B 49152
#define O_C0  65536
#define O_C1  81920
#define O_MEM 98304
#define O_FLAGS 98304
#define O_XI2   102400
#define O_OC2   217824
#define O_LINK  1146880
#define O_PREC  1277952
#define O_RW    1280000
#define O_WW    1288192
#define O_USAGE 1290240
#define STATE_FLOATS 1292288
#define O_BAR  1292288
#define O_XI   1292544
#define O_OUT  1407968
#define F32_END 1424352
#define FULL_BYTE_OFF 5697408ull
#define Y_BYTE_OFF    16183168ull
#define WS_NEED       18280320ull

extern "C" void kernel_launch(void* const* d_in, const int* in_sizes, int n_in,
                              void* d_out, int out_size, void* d_ws, size_t ws_size,
                              hipStream_t stream) {
  (void)in_sizes; (void)n_in; (void)out_size;
  if (ws_size < WS_NEED) return;
  typedef const float* cf;
  cf emb_src = (cf)d_in[0], emb_tgt = (cf)d_in[1];
  cf eW[12], dWt[12];
  for (int i=0;i<12;i++){ eW[i]=(cf)d_in[2+i]; dWt[i]=(cf)d_in[14+i]; }
  cf fcW = (cf)d_in[26], fcb = (cf)d_in[27];
  const int* inp = (const int*)d_in[28];
  const int* tgt = (const int*)d_in[29];
  float* outp = (float*)d_out;
  float* w = (float*)d_ws;

  float* h0buf[2] = { w+O_H0A, w+O_H0B };
  float* h1buf[2] = { w+O_H1A, w+O_H1B };
  float* c0 = w+O_C0;  float* c1 = w+O_C1;
  float* memb = w+O_MEM;
  float* linkb = w+O_LINK; float* precb = w+O_PREC;
  float* rwb = w+O_RW;     float* wwb = w+O_WW;   float* usageb = w+O_USAGE;
  float* xib = w+O_XI;     float* outb = w+O_OUT;
  u16* fullb = (u16*)((char*)d_ws + FULL_BYTE_OFF);
  u16* yb    = (u16*)((char*)d_ws + Y_BYTE_OFF);

  hipMemsetAsync(w, 0, (size_t)(STATE_FLOATS+256)*4, stream);

  StepArgs sa;
  sa.emb[0]=emb_src; sa.emb[1]=emb_tgt;
  sa.seq[0]=inp;     sa.seq[1]=tgt;
  sa.Wx0[0]=eW[0]; sa.Wh0[0]=eW[1]; sa.bx0[0]=eW[2]; sa.bh0[0]=eW[3];
  sa.Wx1[0]=eW[4]; sa.Wh1[0]=eW[5]; sa.bx1[0]=eW[6]; sa.bh1[0]=eW[7];
  sa.Wi[0]=eW[8];  sa.bi[0]=eW[9];
  sa.Wx0[1]=dWt[0]; sa.Wh0[1]=dWt[1]; sa.bx0[1]=dWt[2]; sa.bh0[1]=dWt[3];
  sa.Wx1[1]=dWt[4]; sa.Wh1[1]=dWt[5]; sa.bx1[1]=dWt[6]; sa.bh1[1]=dWt[7];
  sa.Wi[1]=dWt[8];  sa.bi[1]=dWt[9];
  sa.h0[0]=h0buf[0]; sa.h0[1]=h0buf[1];
  sa.h1[0]=h1buf[0]; sa.h1[1]=h1buf[1];
  sa.c0=c0; sa.c1=c1;
  sa.xi2[0]=xib;      sa.xi2[1]=w+O_XI2;
  sa.oc[0]=outb;      sa.oc[1]=w+O_OC2;
  sa.full=fullb;
  sa.flags=(unsigned*)(w + O_FLAGS);
  sa.gen=(unsigned*)(w + O_BAR);

  (void)hipFuncSetAttribute((const void*)k_all,
      hipFuncAttributeMaxDynamicSharedMemorySize, DYN_LDS_BYTES);

  void* kargs[] = { &sa };
  hipError_t err = hipLaunchCooperativeKernel((const void*)k_all, dim3(NBLK), dim3(NTHR),
                                              kargs, DYN_LDS_BYTES, stream);
  if (err != hipSuccess) {
    // fallback: per-step dispatch chain (round-4-verified path, global DNC state)
    int pp = 0;
    for (int t = 0; t < TT; ++t) {
      k_lstm<<<64,256,0,stream>>>(eW[0], NNIN, eW[1], eW[2], eW[3],
                                  emb_src, inp, t, nullptr,
                                  h0buf[pp], h0buf[pp^1], c0, nullptr, nullptr);
      k_lstm<<<64,256,0,stream>>>(eW[4], 512, eW[5], eW[6], eW[7],
                                  nullptr, nullptr, t, h0buf[pp^1],
                                  h1buf[pp], h1buf[pp^1], c1, outb, nullptr);
      k_xi<<<113,256,0,stream>>>(outb, eW[8], eW[9], xib);
      k_mem<<<32,256,0,stream>>>(xib, memb, linkb, precb, rwb, wwb, usageb,
                                 nullptr, t);
      pp ^= 1;
    }
    hipMemsetAsync(w, 0, (size_t)O_MEM*4, stream);
    pp = 0;
    for (int t = 0; t < TT; ++t) {
      k_lstm<<<64,256,0,stream>>>(dWt[0], NNIN, dWt[1], dWt[2], dWt[3],
                                  emb_tgt, tgt, t, nullptr,
                                  h0buf[pp], h0buf[pp^1], c0, nullptr, nullptr);
      k_lstm<<<64,256,0,stream>>>(dWt[4], 512, dWt[5], dWt[6], dWt[7],
                                  nullptr, nullptr, t, h0buf[pp^1],
                                  h1buf[pp], h1buf[pp^1], c1, outb, fullb);
      k_xi<<<113,256,0,stream>>>(outb, dWt[8], dWt[9], xib);
      k_mem<<<32,256,0,stream>>>(xib, memb, linkb, precb, rwb, wwb, usageb,
                                 fullb, t);
      pp ^= 1;
    }
  }

  k_y<<<1024,256,0,stream>>>(fullb, dWt[10], dWt[11], yb);
  k_logits<<<32*157,256,0,stream>>>(yb, fcW, fcb, outp);
}

// Round 19
// 4099.869 us; speedup vs baseline: 1.0436x; 1.0364x over previous
//
#include <hip/hip_runtime.h>

#define BB   32
#define DD   512
#define RR   4
#define MM   64
#define VV   10000
#define TT   64
#define IFX  3607
#define NNIN 2560
#define EPSF 1e-6f

typedef unsigned short u16;

__device__ __forceinline__ float bf(u16 u){ return __uint_as_float(((unsigned)u)<<16); }
__device__ __forceinline__ float4 b4f(ushort4 u){
  float4 f; f.x = bf(u.x); f.y = bf(u.y); f.z = bf(u.z); f.w = bf(u.w); return f;
}
__device__ __forceinline__ u16 f2b(float f){
  unsigned u = __float_as_uint(f);
  u += 0x7fffu + ((u>>16)&1u);
  return (u16)(u>>16);
}
__device__ __forceinline__ float sigmf(float x){ return 1.f/(1.f+__expf(-x)); }
__device__ __forceinline__ float softplusf(float x){ return x > 20.f ? x : log1pf(__expf(x)); }
__device__ __forceinline__ float wredSum(float v){
  #pragma unroll
  for (int s=1;s<64;s<<=1) v += __shfl_xor(v,s,64);
  return v;
}
__device__ __forceinline__ float wredMax(float v){
  #pragma unroll
  for (int s=1;s<64;s<<=1) v = fmaxf(v, __shfl_xor(v,s,64));
  return v;
}

// LLC-coherent scalar access (agent scope)
__device__ __forceinline__ float ldg_c(const float* p){
  return __hip_atomic_load(const_cast<float*>(p), __ATOMIC_RELAXED, __HIP_MEMORY_SCOPE_AGENT);
}
__device__ __forceinline__ void stg_c(float* p, float v){
  __hip_atomic_store(p, v, __ATOMIC_RELAXED, __HIP_MEMORY_SCOPE_AGENT);
}
__device__ __forceinline__ unsigned ldg_cu(const unsigned* p){
  return __hip_atomic_load(const_cast<unsigned*>(p), __ATOMIC_RELAXED, __HIP_MEMORY_SCOPE_AGENT);
}
__device__ __forceinline__ void stg_cu(unsigned* p, unsigned v){
  __hip_atomic_store(p, v, __ATOMIC_RELAXED, __HIP_MEMORY_SCOPE_AGENT);
}

// Batched agent-scope loads (sc1 only: LLC-coherent, LLC-cacheable).
__device__ __forceinline__ void ldg_cv4x2(const float* p0,const float* p1, float4& a,float4& b){
  asm volatile("global_load_dwordx4 %0, %2, off sc1\n\t"
               "global_load_dwordx4 %1, %3, off sc1\n\t"
               "s_waitcnt vmcnt(0)"
               : "=&v"(a),"=&v"(b)
               : "v"(p0),"v"(p1)
               : "memory");
}
__device__ __forceinline__ void ldg_c4s(const float* p0,const float* p1,const float* p2,const float* p3,
                                        float& a,float& b,float& c,float& d){
  asm volatile("global_load_dword %0, %4, off sc1\n\t"
               "global_load_dword %1, %5, off sc1\n\t"
               "global_load_dword %2, %6, off sc1\n\t"
               "global_load_dword %3, %7, off sc1\n\t"
               "s_waitcnt vmcnt(0)"
               : "=&v"(a),"=&v"(b),"=&v"(c),"=&v"(d)
               : "v"(p0),"v"(p1),"v"(p2),"v"(p3)
               : "memory");
}
__device__ __forceinline__ void ldg_c2s(const float* p0,const float* p1, float& a,float& b){
  asm volatile("global_load_dword %0, %2, off sc1\n\t"
               "global_load_dword %1, %3, off sc1\n\t"
               "s_waitcnt vmcnt(0)"
               : "=&v"(a),"=&v"(b)
               : "v"(p0),"v"(p1)
               : "memory");
}

#define SM_FLOATS 9600
#define NBLK 256u
#define NTHR 512

// ---- grid barrier v6: all blocks poll all 256 flags (no master/gen) ----
__device__ __forceinline__ void gbar6(unsigned* flags, unsigned ep){
  asm volatile("s_waitcnt vmcnt(0) lgkmcnt(0)" ::: "memory");
  __syncthreads();
  if (threadIdx.x == 0) stg_cu(&flags[blockIdx.x*16], ep);
  if (threadIdx.x < 256) {
    const unsigned* f = &flags[threadIdx.x*16];
    while (ldg_cu(f) < ep) __builtin_amdgcn_s_sleep(1);
  }
  __syncthreads();
}

// =============== persistent-W LDS layouts ===============
#define LW_OFF 5312
#define XW_OFF 4224

__device__ __forceinline__ void preload_lstm(float* S, int tile,
    const float* __restrict__ Wx, int wx_stride, const float* __restrict__ Wh)
{
  float* WL = S + LW_OFF;
  const int tid = threadIdx.x;
  const int dblk = tile*8;
  for (int i = tid; i < 8192; i += NTHR) {
    const int r  = i >> 8;
    const int k4 = (i & 255) * 4;
    const int gr = ((r>>3)<<9) + dblk + (r&7);
    float4 v;
    if (k4 < 512) v = *(const float4*)&Wx[(size_t)gr*wx_stride + k4];
    else          v = *(const float4*)&Wh[(size_t)gr*512 + (k4-512)];
    *(float4*)&WL[r*1028 + k4] = v;
  }
}

__device__ __forceinline__ void preload_xi(float* S, int xtile, const float* __restrict__ Wi){
  float* XW = S + XW_OFF;
  const int tid = threadIdx.x;
  for (int i = tid; i < 8192; i += NTHR) {
    const int r  = i >> 7;
    const int k4 = (i & 127) * 4;
    int cr = xtile*64 + r; if (cr >= IFX) cr = IFX-1;
    *(float4*)&XW[r*516 + k4] = *(const float4*)&Wi[(size_t)cr*512 + k4];
  }
}

// ---- LSTM gates GEMM: 4 batches x 4 gates register tile, K-split-8 ----
__device__ __noinline__ void lstm_tile_p(
    float* S, int tile,
    const float* __restrict__ bx, const float* __restrict__ bh,
    const float* emb, const int* seq, int t,
    const float* xf,
    const float* hprev, float* hcur,
    float* cst, float* outc, u16* full)
{
  float (*As)[132] = (float(*)[132])S;
  int* idxs = (int*)(S + 5280);
  const float* WL = S + LW_OFF;
  const int tid = threadIdx.x;
  const int w  = tid >> 6;          // wave = d-element 0..7
  const int bg = (tid >> 3) & 7;    // batch group
  const int ks = tid & 7;           // K-slice
  const int dblk = tile * 8;
  const int ba = tid >> 5;          // staging batch a (0..15)
  const int bbs = ba + 16;          // staging batch b (16..31)
  const int f0 = (tid & 31) * 4;    // staging f4 offset
  float acc[4][4];
  #pragma unroll
  for (int i=0;i<4;i++)
    #pragma unroll
    for (int j=0;j<4;j++) acc[i][j]=0.f;
  if (emb != nullptr && tid < 32) idxs[tid] = seq[tid*64 + t];
  __syncthreads();
  #define LSRC(ch, bb_) ( ((ch) < 4) \
      ? ((emb != nullptr) ? &emb[(size_t)idxs[bb_]*512 + (ch)*128 + f0] \
                          : &xf[(bb_)*512 + (ch)*128 + f0]) \
      : &hprev[(bb_)*512 + ((ch)*128 - 512) + f0] )
  for (int chunk = 0; chunk < 8; ++chunk) {
    {
      float4 v0, v1;
      ldg_cv4x2(LSRC(chunk,ba), LSRC(chunk,bbs), v0, v1);
      *(float4*)&As[ba][f0]  = v0;
      *(float4*)&As[bbs][f0] = v1;
    }
    __syncthreads();
    const int kb = chunk*128;
    #pragma unroll
    for (int m = 0; m < 4; ++m) {
      const int kk = ks*4 + m*32;
      float4 w4[4], a4[4];
      #pragma unroll
      for (int j=0;j<4;j++) w4[j] = *(const float4*)&WL[(w + 8*j)*1028 + kb + kk];
      #pragma unroll
      for (int i=0;i<4;i++) a4[i] = *(const float4*)&As[bg + 8*i][kk];
      #pragma unroll
      for (int i=0;i<4;i++)
        #pragma unroll
        for (int j=0;j<4;j++)
          acc[i][j] = fmaf(a4[i].x,w4[j].x, fmaf(a4[i].y,w4[j].y,
                      fmaf(a4[i].z,w4[j].z, fmaf(a4[i].w,w4[j].w, acc[i][j]))));
    }
    __syncthreads();
  }
  #undef LSRC
  // reduce over ks (8 lanes)
  #pragma unroll
  for (int i=0;i<4;i++)
    #pragma unroll
    for (int j=0;j<4;j++){
      float v = acc[i][j];
      v += __shfl_xor(v,1,64);
      v += __shfl_xor(v,2,64);
      v += __shfl_xor(v,4,64);
      acc[i][j] = v;
    }
  if (ks == 0) {
    const int d = dblk + w;
    float bias[4];
    #pragma unroll
    for (int j=0;j<4;j++){
      const int gcol = (j<<9) + d;
      bias[j] = bx[gcol] + bh[gcol];
    }
    #pragma unroll
    for (int i=0;i<4;i++){
      const int b = bg + 8*i;
      const int cid = b*512 + d;
      const float gi = acc[i][0] + bias[0];
      const float gf = acc[i][1] + bias[1];
      const float gg = acc[i][2] + bias[2];
      const float go = acc[i][3] + bias[3];
      const float cv = sigmf(gf)*cst[cid] + sigmf(gi)*tanhf(gg);
      const float hv = sigmf(go)*tanhf(cv);
      cst[cid] = cv;
      stg_c(&hcur[cid], hv);
      if (outc != nullptr) {
        const float oc = fminf(fmaxf(hv,-20.f),20.f);
        stg_c(&outc[cid], oc);
        if (full != nullptr) full[((size_t)t*32 + b)*2560 + d] = f2b(oc);
      }
    }
  }
  __syncthreads();
}

// ---- xi tile: 4 batches x 4 cols register tile, K-split-4 ----
__device__ __noinline__ void xi_tile_p(
    float* S, int xtile,
    const float* outc, const float* __restrict__ bi, float* xi)
{
  float (*As)[132] = (float(*)[132])S;
  const float* XW = S + XW_OFF;
  const int tid = threadIdx.x;
  const int w  = tid >> 6;
  const int l  = tid & 63;
  const int tt = l >> 2;
  const int ks = l & 3;
  const int cg = 2*w + (tt>>3);
  const int bg = tt & 7;
  const int ba = tid >> 5;
  const int bbs = ba + 16;
  const int f0 = (tid & 31) * 4;
  float acc[4][4];
  #pragma unroll
  for (int i=0;i<4;i++)
    #pragma unroll
    for (int j=0;j<4;j++) acc[i][j]=0.f;
  for (int chunk = 0; chunk < 4; ++chunk) {
    {
      const int kb0 = chunk*128;
      float4 v0, v1;
      ldg_cv4x2(&outc[ba*512 + kb0 + f0], &outc[bbs*512 + kb0 + f0], v0, v1);
      *(float4*)&As[ba][f0]  = v0;
      *(float4*)&As[bbs][f0] = v1;
    }
    __syncthreads();
    const int kb = chunk*128;
    #pragma unroll
    for (int m = 0; m < 8; ++m) {
      const int kk = ks*4 + m*16;
      float4 w4[4], a4[4];
      #pragma unroll
      for (int j=0;j<4;j++) w4[j] = *(const float4*)&XW[(cg + 16*j)*516 + kb + kk];
      #pragma unroll
      for (int i=0;i<4;i++) a4[i] = *(const float4*)&As[bg + 8*i][kk];
      #pragma unroll
      for (int i=0;i<4;i++)
        #pragma unroll
        for (int j=0;j<4;j++)
          acc[i][j] = fmaf(a4[i].x,w4[j].x, fmaf(a4[i].y,w4[j].y,
                      fmaf(a4[i].z,w4[j].z, fmaf(a4[i].w,w4[j].w, acc[i][j]))));
    }
    __syncthreads();
  }
  // reduce over ks (4 lanes)
  #pragma unroll
  for (int i=0;i<4;i++)
    #pragma unroll
    for (int j=0;j<4;j++){
      float v = acc[i][j];
      v += __shfl_xor(v,1,64);
      v += __shfl_xor(v,2,64);
      acc[i][j] = v;
    }
  if (ks == 0) {
    #pragma unroll
    for (int j=0;j<4;j++){
      const int col = xtile*64 + cg + 16*j;
      if (col < IFX) {
        const float bias = bi[col];
        #pragma unroll
        for (int i=0;i<4;i++)
          stg_c(&xi[(size_t)(bg + 8*i)*IFX + col], acc[i][j] + bias);
      }
    }
  }
  __syncthreads();
}

__device__ __constant__ int kSidx[23] = {
  2048,2049,2050,2051, 2564, 3589,3590,3591,3592, 3593, 3594,
  3595,3596,3597, 3598,3599,3600, 3601,3602,3603, 3604,3605,3606
};

// ===================== LDS-persistent DNC memory step (512 thr) =====================
#define MEMPITCH 516
#define L_MEM   0
#define L_LINK  33024
#define L_RK    37184
#define L_WK    39232
#define L_RWP   39744
#define L_PREC  40000
#define L_USAGE 40064
#define L_WCW   40128
#define L_U     40192
#define L_WW    40256
#define L_CWA   40320
#define L_SC    40576
#define L_SRAW  40616
#define L_END   40640
#define DYN_LDS_BYTES 162560

__device__ __noinline__ void mem_tile_lds(
    float* S, int b, const float* xi, u16* full, int t)
{
  const int tid = threadIdx.x;
  const float* xb = xi + (size_t)b*IFX;
  float* MEMS = S + L_MEM;
  float* LNK  = S + L_LINK;
  float (*rk_s)[512] = (float(*)[512])(S + L_RK);
  float* wk_s  = S + L_WK;
  float* RWP   = S + L_RWP;
  float* PREC  = S + L_PREC;
  float* USAGE = S + L_USAGE;
  float* wcw_s = S + L_WCW;
  float* u_s   = S + L_U;
  float* WW    = S + L_WW;
  float* sorted_s = S + L_CWA;
  float* excl_s   = S + L_CWA + 64;
  int*   rank_s   = (int*)(S + L_CWA + 128);
  float (*cw_s)[64] = (float(*)[64])(S + L_CWA);
  float* sc   = S + L_SC;
  float* sraw = S + L_SRAW;

  {
    const float* base = xb + tid*4;
    float v0,v1,v2,v3;
    ldg_c4s(base+0,base+1,base+2,base+3, v0,v1,v2,v3);
    float* d = &rk_s[tid>>7][(tid&127)*4];
    d[0]=tanhf(v0); d[1]=tanhf(v1); d[2]=tanhf(v2); d[3]=tanhf(v3);
  }
  if (tid < 128) {
    const float* base = xb + 2052 + tid*4;
    float v0,v1,v2,v3;
    ldg_c4s(base+0,base+1,base+2,base+3, v0,v1,v2,v3);
    float* d = &wk_s[tid*4];
    d[0]=tanhf(v0); d[1]=tanhf(v1); d[2]=tanhf(v2); d[3]=tanhf(v3);
  }
  if (tid < 23) sraw[tid] = ldg_c(&xb[kSidx[tid]]);
  __syncthreads();
  if (tid == 0) {
    for (int r=0;r<4;r++) sc[r] = softplusf(sraw[r]);
    sc[4] = softplusf(sraw[4]);
    for (int r=0;r<4;r++) sc[5+r] = sigmf(sraw[5+r]);
    sc[9]  = sigmf(sraw[9]);
    sc[10] = sigmf(sraw[10]);
    for (int r=0;r<4;r++) {
      const float a0=sraw[11+3*r], a1=sraw[12+3*r], a2=sraw[13+3*r];
      const float mx=fmaxf(a0,fmaxf(a1,a2));
      const float e0=__expf(a0-mx), e1=__expf(a1-mx), e2=__expf(a2-mx);
      const float s=e0+e1+e2;
      sc[11+3*r]=e0/s; sc[12+3*r]=e1/s; sc[13+3*r]=e2/s;
    }
  }
  if (tid < 256) {
    const int wid = tid>>6, ln = tid&63;
    float p = 0.f;
    for (int i = ln; i < 512; i += 64) { const float v = rk_s[wid][i]; p = fmaf(v,v,p); }
    p = wredSum(p);
    if (ln == 0) sc[24+wid] = sqrtf(p);
    if (wid == 1) {
      float q2 = 0.f;
      for (int i = ln; i < 512; i += 64) { const float v = wk_s[i]; q2 = fmaf(v,v,q2); }
      q2 = wredSum(q2);
      if (ln == 0) sc[23] = sqrtf(q2);
    }
  }
  __syncthreads();
  if (tid < 256) {
    const int m = tid>>2, q = tid&3;
    const float* mr = MEMS + m*MEMPITCH;
    float d = 0.f, ss = 0.f;
    for (int i = q*128; i < q*128+128; i += 4) {
      const float4 mv = *(const float4*)&mr[i];
      d = fmaf(mv.x, wk_s[i  ], d); d = fmaf(mv.y, wk_s[i+1], d);
      d = fmaf(mv.z, wk_s[i+2], d); d = fmaf(mv.w, wk_s[i+3], d);
      ss = fmaf(mv.x,mv.x,ss); ss = fmaf(mv.y,mv.y,ss);
      ss = fmaf(mv.z,mv.z,ss); ss = fmaf(mv.w,mv.w,ss);
    }
    d  += __shfl_xor(d,1,64);  d  += __shfl_xor(d,2,64);
    ss += __shfl_xor(ss,1,64); ss += __shfl_xor(ss,2,64);
    if (q == 0) wcw_s[m] = d / ((sqrtf(ss)+EPSF)*(sc[23]+EPSF)) * sc[4];
  }
  if (tid < 64) {
    const float uo = USAGE[tid];
    float u = uo + (1.f-uo)*WW[tid];
    #pragma unroll
    for (int r=0;r<4;r++) u *= (1.f - sc[5+r]*RWP[r*64+tid]);
    USAGE[tid] = u;
  }
  __syncthreads();
  if (tid < 64) {
    const float v = wcw_s[tid];
    const float mx = wredMax(v);
    const float e = __expf(v-mx);
    const float s2 = wredSum(e);
    wcw_s[tid] = e/s2;
    u_s[tid] = EPSF + (1.f-EPSF)*USAGE[tid];
  }
  __syncthreads();
  if (tid < 64) {
    const float u = u_s[tid]; int rk2 = 0;
    for (int j=0;j<64;j++){ const float uj = u_s[j]; rk2 += (uj<u) || (uj==u && j<tid); }
    rank_s[tid] = rk2; sorted_s[rk2] = u;
  }
  __syncthreads();
  // exclusive cumprod via wave shfl_up scan (lanes 0..63)
  if (tid < 64) {
    float v = sorted_s[tid];
    float inc = v;
    #pragma unroll
    for (int s=1;s<64;s<<=1){
      const float tshf = __shfl_up(inc, s, 64);
      if (tid >= s) inc *= tshf;
    }
    float exc = __shfl_up(inc, 1, 64);
    if (tid == 0) exc = 1.f;
    excl_s[tid] = exc;
  }
  __syncthreads();
  if (tid < 64) {
    const float al = (1.f - u_s[tid]) * excl_s[rank_s[tid]];
    const float wwv = sc[10]*(sc[9]*al + (1.f-sc[9])*wcw_s[tid]);
    WW[tid] = wwv;
    const float s3 = wredSum(wwv);
    if (tid==0) sc[28] = s3;
  }
  __syncthreads();
  {
    float e0,w0;
    ldg_c2s(&xb[2565+tid], &xb[3077+tid], e0, w0);
    const float er0 = sigmf(e0);
    const float wv0 = tanhf(w0);
    #pragma unroll 4
    for (int m=0;m<64;m++){
      const float wwm = WW[m];
      float* p = MEMS + m*MEMPITCH + tid;
      p[0] = p[0]*(1.f - wwm*er0) + wwm*wv0;
    }
  }
  __syncthreads();
  for (int e = tid; e < 4096; e += NTHR) {
    const int i2 = e>>6, j2 = e&63;
    const float lv = LNK[i2*65+j2];
    LNK[i2*65+j2] = (i2==j2) ? 0.f
               : ((1.f - WW[i2] - WW[j2])*lv + WW[i2]*PREC[j2]);
  }
  __syncthreads();
  if (tid < 64) PREC[tid] = (1.f - sc[28])*PREC[tid] + WW[tid];
  __syncthreads();
  const int r6 = tid>>6, m6 = tid&63;
  if (tid < 256) {
    const float* mr = MEMS + m6*MEMPITCH;
    const float* rkr = rk_s[r6];
    float d = 0.f, ss = 0.f;
    for (int i=0;i<512;i+=4){
      const float4 mv = *(const float4*)&mr[i];
      d = fmaf(mv.x, rkr[i  ], d); d = fmaf(mv.y, rkr[i+1], d);
      d = fmaf(mv.z, rkr[i+2], d); d = fmaf(mv.w, rkr[i+3], d);
      ss = fmaf(mv.x,mv.x,ss); ss = fmaf(mv.y,mv.y,ss);
      ss = fmaf(mv.z,mv.z,ss); ss = fmaf(mv.w,mv.w,ss);
    }
    const float cv = d / ((sqrtf(ss)+EPSF)*(sc[24+r6]+EPSF)) * sc[r6];
    const float mx = wredMax(cv);
    const float e = __expf(cv-mx);
    const float s2 = wredSum(e);
    cw_s[r6][m6] = e/s2;
  }
  __syncthreads();
  float rn = 0.f;
  if (tid < 256) {
    float fw = 0.f, bw = 0.f;
    #pragma unroll 8
    for (int m3=0;m3<64;m3++){
      const float rp = RWP[r6*64+m3];
      fw = fmaf(LNK[m6*65+m3], rp, fw);
      bw = fmaf(LNK[m3*65+m6], rp, bw);
    }
    rn = sc[11+3*r6]*bw + sc[12+3*r6]*fw + sc[13+3*r6]*cw_s[r6][m6];
  }
  __syncthreads();
  if (tid < 256) RWP[r6*64+m6] = rn;
  __syncthreads();
  if (full != nullptr && tid < 256) {
    const int l = tid&63, r8 = tid>>6;
    float a[8];
    #pragma unroll
    for (int j=0;j<8;j++) a[j]=0.f;
    for (int m3=0;m3<64;m3++){
      const float rv_ = RWP[r8*64+m3];
      const float* mr = MEMS + m3*MEMPITCH + 2*l;
      #pragma unroll
      for (int j=0;j<4;j++){
        const float2 v = *(const float2*)&mr[128*j];
        a[2*j]   = fmaf(rv_, v.x, a[2*j]);
        a[2*j+1] = fmaf(rv_, v.y, a[2*j+1]);
      }
    }
    u16* dst = full + ((size_t)t*32 + b)*2560 + 512 + r8*512;
    #pragma unroll
    for (int j=0;j<4;j++){
      const unsigned wd = (unsigned)f2b(a[2*j]) | ((unsigned)f2b(a[2*j+1])<<16);
      *(unsigned*)&dst[2*l + 128*j] = wd;
    }
  }
  __syncthreads();
}

// ======= fallback-path tiles (round-4-verified, 256 thr, global W) =======
__device__ __noinline__ void lstm_tile_g(
    float* sm, int tile,
    const float* __restrict__ Wx, int wx_stride,
    const float* __restrict__ Wh,
    const float* __restrict__ bx, const float* __restrict__ bh,
    const float* emb, const int* seq, int t,
    const float* xf,
    const float* hprev, float* hcur,
    float* cst, float* outc, u16* full)
{
  float (*As)[132] = (float(*)[132])sm;
  float (*Ws)[132] = (float(*)[132])(sm + 4224);
  float* gs = sm + 8448;
  int* idxs = (int*)(sm + 9504);
  const int tid = threadIdx.x;
  const int c = tid & 31;
  const int dblk = tile * 8;
  const int gcol = ((c>>3)<<9) + dblk + (c&7);
  const int b0 = (tid >> 5) * 4;
  float acc0=0.f, acc1=0.f, acc2=0.f, acc3=0.f;
  if (emb != nullptr && tid < 32) idxs[tid] = seq[tid*64 + t];
  __syncthreads();
  for (int chunk = 0; chunk < 8; ++chunk) {
    const int k0 = chunk * 128;
    const bool xp = (chunk < 4);
    for (int i = tid; i < 1024; i += 256) {
      const int bb2 = i >> 5, f4i = (i & 31)*4;
      if (xp && emb != nullptr) {
        *(float4*)&As[bb2][f4i] = *(const float4*)&emb[(size_t)idxs[bb2]*512 + k0 + f4i];
      } else {
        const float* src = xp ? &xf[bb2*512 + k0 + f4i]
                              : &hprev[bb2*512 + (k0-512) + f4i];
        As[bb2][f4i+0] = ldg_c(src+0);
        As[bb2][f4i+1] = ldg_c(src+1);
        As[bb2][f4i+2] = ldg_c(src+2);
        As[bb2][f4i+3] = ldg_c(src+3);
      }
    }
    for (int i = tid; i < 1024; i += 256) {
      const int r = i >> 5, f4i = (i & 31)*4;
      const int gr = ((r>>3)<<9) + dblk + (r&7);
      const float4 v = xp ? *(const float4*)&Wx[(size_t)gr*wx_stride + k0 + f4i]
                          : *(const float4*)&Wh[(size_t)gr*512 + (k0-512) + f4i];
      *(float4*)&Ws[r][f4i] = v;
    }
    __syncthreads();
    #pragma unroll 8
    for (int kk = 0; kk < 128; kk += 4) {
      const float4 w4 = *(const float4*)&Ws[c][kk];
      const float4 a0 = *(const float4*)&As[b0+0][kk];
      const float4 a1 = *(const float4*)&As[b0+1][kk];
      const float4 a2 = *(const float4*)&As[b0+2][kk];
      const float4 a3 = *(const float4*)&As[b0+3][kk];
      acc0 = fmaf(a0.x,w4.x,fmaf(a0.y,w4.y,fmaf(a0.z,w4.z,fmaf(a0.w,w4.w,acc0))));
      acc1 = fmaf(a1.x,w4.x,fmaf(a1.y,w4.y,fmaf(a1.z,w4.z,fmaf(a1.w,w4.w,acc1))));
      acc2 = fmaf(a2.x,w4.x,fmaf(a2.y,w4.y,fmaf(a2.z,w4.z,fmaf(a2.w,w4.w,acc2))));
      acc3 = fmaf(a3.x,w4.x,fmaf(a3.y,w4.y,fmaf(a3.z,w4.z,fmaf(a3.w,w4.w,acc3))));
    }
    __syncthreads();
  }
  const float bias = bx[gcol] + bh[gcol];
  gs[c*33 + b0+0] = acc0 + bias;
  gs[c*33 + b0+1] = acc1 + bias;
  gs[c*33 + b0+2] = acc2 + bias;
  gs[c*33 + b0+3] = acc3 + bias;
  __syncthreads();
  {
    const int b2 = tid & 31, dl2 = tid >> 5;
    const float gi = gs[(0*8+dl2)*33 + b2];
    const float gf = gs[(1*8+dl2)*33 + b2];
    const float gg = gs[(2*8+dl2)*33 + b2];
    const float go = gs[(3*8+dl2)*33 + b2];
    const int d = dblk + dl2;
    const int cid = b2*512 + d;
    const float cv = sigmf(gf)*cst[cid] + sigmf(gi)*tanhf(gg);
    const float hv = sigmf(go)*tanhf(cv);
    cst[cid] = cv;
    stg_c(&hcur[cid], hv);
    if (outc != nullptr) {
      const float oc = fminf(fmaxf(hv,-20.f),20.f);
      stg_c(&outc[cid], oc);
      if (full != nullptr) full[((size_t)t*32 + b2)*2560 + d] = f2b(oc);
    }
  }
  __syncthreads();
}

__device__ __noinline__ void xi_tile_g(
    float* sm, int tile,
    const float* outc,
    const float* __restrict__ Wi, const float* __restrict__ bi,
    float* xi)
{
  float (*As)[132] = (float(*)[132])sm;
  float (*Ws)[132] = (float(*)[132])(sm + 4224);
  const int tid = threadIdx.x;
  const int c = tid & 31;
  const int col = tile*32 + c;
  const int b0 = (tid>>5)*4;
  float acc0=0.f,acc1=0.f,acc2=0.f,acc3=0.f;
  for (int chunk = 0; chunk < 4; ++chunk) {
    const int k0 = chunk*128;
    for (int i = tid; i < 1024; i += 256) {
      const int bb2 = i>>5, f4i = (i&31)*4;
      const float* src = &outc[bb2*512 + k0 + f4i];
      As[bb2][f4i+0] = ldg_c(src+0);
      As[bb2][f4i+1] = ldg_c(src+1);
      As[bb2][f4i+2] = ldg_c(src+2);
      As[bb2][f4i+3] = ldg_c(src+3);
    }
    for (int i = tid; i < 1024; i += 256) {
      const int r = i>>5, f4i = (i&31)*4;
      int cr = tile*32 + r; cr = cr < IFX ? cr : IFX-1;
      *(float4*)&Ws[r][f4i] = *(const float4*)&Wi[(size_t)cr*512 + k0 + f4i];
    }
    __syncthreads();
    #pragma unroll 8
    for (int kk = 0; kk < 128; kk += 4) {
      const float4 w4 = *(const float4*)&Ws[c][kk];
      const float4 a0 = *(const float4*)&As[b0+0][kk];
      const float4 a1 = *(const float4*)&As[b0+1][kk];
      const float4 a2 = *(const float4*)&As[b0+2][kk];
      const float4 a3 = *(const float4*)&As[b0+3][kk];
      acc0 = fmaf(a0.x,w4.x,fmaf(a0.y,w4.y,fmaf(a0.z,w4.z,fmaf(a0.w,w4.w,acc0))));
      acc1 = fmaf(a1.x,w4.x,fmaf(a1.y,w4.y,fmaf(a1.z,w4.z,fmaf(a1.w,w4.w,acc1))));
      acc2 = fmaf(a2.x,w4.x,fmaf(a2.y,w4.y,fmaf(a2.z,w4.z,fmaf(a2.w,w4.w,acc2))));
      acc3 = fmaf(a3.x,w4.x,fmaf(a3.y,w4.y,fmaf(a3.z,w4.z,fmaf(a3.w,w4.w,acc3))));
    }
    __syncthreads();
  }
  if (col < IFX) {
    const float bias = bi[col];
    stg_c(&xi[(size_t)(b0+0)*IFX + col], acc0 + bias);
    stg_c(&xi[(size_t)(b0+1)*IFX + col], acc1 + bias);
    stg_c(&xi[(size_t)(b0+2)*IFX + col], acc2 + bias);
    stg_c(&xi[(size_t)(b0+3)*IFX + col], acc3 + bias);
  }
  __syncthreads();
}

__device__ __noinline__ void mem_tile_g(
    float* sm, int b,
    const float* xi,
    float* mem,
    float* link, float* prec,
    float* rwg, float* wwg, float* usg,
    u16* full, int t)
{
  const int tid = threadIdx.x;
  const float* xb = xi + (size_t)b*IFX;
  float (*rk_s)[512]  = (float(*)[512])sm;
  float* wk_s   = sm + 2048;
  float* er_s   = sm + 2560;
  float* wv_s   = sm + 3072;
  float (*rwp_s)[64]  = (float(*)[64])(sm + 3584);
  float* prec_s = sm + 3840;
  float* usage_s= sm + 3904;
  float* wcw_s  = sm + 3968;
  float* u_s    = sm + 4032;
  float* ww_s   = sm + 4096;
  float* sorted_s = sm + 4160;
  float* excl_s = sm + 4224;
  int*   rank_s = (int*)(sm + 4288);
  float (*cw_s)[64]  = (float(*)[64])(sm + 4352);
  float (*rwn_s)[64] = (float(*)[64])(sm + 4608);
  float* mn_s   = sm + 4864;
  float* sc     = sm + 4928;
  float (*link_s)[65] = (float(*)[65])(sm + 4976);

  for (int i = tid; i < 2048; i += 256) rk_s[i>>9][i&511] = tanhf(ldg_c(&xb[i]));
  for (int i = tid; i < 512; i += 256) {
    wk_s[i] = tanhf(ldg_c(&xb[2052+i]));
    er_s[i] = sigmf(ldg_c(&xb[2565+i]));
    wv_s[i] = tanhf(ldg_c(&xb[3077+i]));
  }
  rwp_s[tid>>6][tid&63] = rwg[b*256 + tid];
  if (tid < 64) { prec_s[tid] = prec[b*64+tid]; usage_s[tid] = usg[b*64+tid]; }
  if (tid == 0) {
    for (int r=0;r<4;r++) sc[r] = softplusf(ldg_c(&xb[2048+r]));
    sc[4] = softplusf(ldg_c(&xb[2564]));
    for (int r=0;r<4;r++) sc[5+r] = sigmf(ldg_c(&xb[3589+r]));
    sc[9]  = sigmf(ldg_c(&xb[3593]));
    sc[10] = sigmf(ldg_c(&xb[3594]));
    for (int r=0;r<4;r++) {
      const float a0=ldg_c(&xb[3595+3*r]), a1=ldg_c(&xb[3596+3*r]), a2=ldg_c(&xb[3597+3*r]);
      const float mx=fmaxf(a0,fmaxf(a1,a2));
      const float e0=__expf(a0-mx), e1=__expf(a1-mx), e2=__expf(a2-mx);
      const float s=e0+e1+e2;
      sc[11+3*r]=e0/s; sc[12+3*r]=e1/s; sc[13+3*r]=e2/s;
    }
  }
  __syncthreads();
  {
    const int wid = tid>>6, ln = tid&63;
    float p = 0.f;
    for (int i = ln; i < 512; i += 64) { const float v = rk_s[wid][i]; p = fmaf(v,v,p); }
    p = wredSum(p);
    if (ln == 0) sc[24+wid] = sqrtf(p);
    if (wid == 1) {
      float q2 = 0.f;
      for (int i = ln; i < 512; i += 64) { const float v = wk_s[i]; q2 = fmaf(v,v,q2); }
      q2 = wredSum(q2);
      if (ln == 0) sc[23] = sqrtf(q2);
    }
  }
  __syncthreads();
  {
    const int m = tid>>2, q = tid&3;
    const float* mr = mem + ((size_t)b*64 + m)*512;
    float d = 0.f, ss = 0.f;
    for (int i = q*128; i < q*128+128; i += 4) {
      const float4 mv = *(const float4*)&mr[i];
      d = fmaf(mv.x, wk_s[i  ], d); d = fmaf(mv.y, wk_s[i+1], d);
      d = fmaf(mv.z, wk_s[i+2], d); d = fmaf(mv.w, wk_s[i+3], d);
      ss = fmaf(mv.x,mv.x,ss); ss = fmaf(mv.y,mv.y,ss);
      ss = fmaf(mv.z,mv.z,ss); ss = fmaf(mv.w,mv.w,ss);
    }
    d  += __shfl_xor(d,1,64);  d  += __shfl_xor(d,2,64);
    ss += __shfl_xor(ss,1,64); ss += __shfl_xor(ss,2,64);
    if (q == 0) wcw_s[m] = d / ((sqrtf(ss)+EPSF)*(sc[23]+EPSF)) * sc[4];
  }
  if (tid < 64) {
    const float uo = usage_s[tid];
    const float wwp = wwg[b*64+tid];
    float u = uo + (1.f-uo)*wwp;
    #pragma unroll
    for (int r=0;r<4;r++) u *= (1.f - sc[5+r]*rwp_s[r][tid]);
    usage_s[tid] = u; usg[b*64+tid] = u;
  }
  __syncthreads();
  if (tid < 64) {
    const float v = wcw_s[tid];
    const float mx = wredMax(v);
    const float e = __expf(v-mx);
    const float s2 = wredSum(e);
    wcw_s[tid] = e/s2;
    u_s[tid] = EPSF + (1.f-EPSF)*usage_s[tid];
  }
  __syncthreads();
  if (tid < 64) {
    const float u = u_s[tid]; int rk2 = 0;
    for (int j=0;j<64;j++){ const float uj = u_s[j]; rk2 += (uj<u) || (uj==u && j<tid); }
    rank_s[tid] = rk2; sorted_s[rk2] = u;
  }
  __syncthreads();
  if (tid == 0) { float run = 1.f; for (int p2=0;p2<64;p2++){ excl_s[p2]=run; run*=sorted_s[p2]; } }
  __syncthreads();
  if (tid < 64) {
    const float al = (1.f - u_s[tid]) * excl_s[rank_s[tid]];
    const float wwv = sc[10]*(sc[9]*al + (1.f-sc[9])*wcw_s[tid]);
    ww_s[tid] = wwv; wwg[b*64+tid] = wwv;
    const float s3 = wredSum(wwv);
    if (tid==0) sc[28] = s3;
  }
  __syncthreads();
  {
    const int m = tid>>2, q = tid&3;
    const float wwm = ww_s[m];
    float* mr = mem + ((size_t)b*64 + m)*512;
    float ss = 0.f;
    for (int i = q*128; i < q*128+128; i += 4) {
      float4 mv = *(const float4*)&mr[i];
      mv.x = mv.x*(1.f - wwm*er_s[i  ]) + wwm*wv_s[i  ];
      mv.y = mv.y*(1.f - wwm*er_s[i+1]) + wwm*wv_s[i+1];
      mv.z = mv.z*(1.f - wwm*er_s[i+2]) + wwm*wv_s[i+2];
      mv.w = mv.w*(1.f - wwm*er_s[i+3]) + wwm*wv_s[i+3];
      *(float4*)&mr[i] = mv;
      ss += mv.x*mv.x + mv.y*mv.y + mv.z*mv.z + mv.w*mv.w;
    }
    ss += __shfl_xor(ss,1,64); ss += __shfl_xor(ss,2,64);
    if (q==0) mn_s[m] = sqrtf(ss);
  }
  __syncthreads();
  {
    float* lrow = link + (size_t)b*4096;
    for (int e = tid; e < 4096; e += 256) {
      const int i2 = e>>6, j2 = e&63;
      const float ln2 = (i2==j2) ? 0.f
                 : ((1.f - ww_s[i2] - ww_s[j2])*lrow[e] + ww_s[i2]*prec_s[j2]);
      link_s[i2][j2] = ln2;
      lrow[e] = ln2;
    }
  }
  if (tid < 64) prec[b*64+tid] = (1.f - sc[28])*prec_s[tid] + ww_s[tid];
  __syncthreads();
  const int r6 = tid>>6, m6 = tid&63;
  {
    const float* mr = mem + ((size_t)b*64 + m6)*512;
    const float* rkr = rk_s[r6];
    float d = 0.f;
    for (int i=0;i<512;i+=4){
      const float4 mv = *(const float4*)&mr[i];
      d = fmaf(mv.x, rkr[i  ], d); d = fmaf(mv.y, rkr[i+1], d);
      d = fmaf(mv.z, rkr[i+2], d); d = fmaf(mv.w, rkr[i+3], d);
    }
    const float cv = d / ((mn_s[m6]+EPSF)*(sc[24+r6]+EPSF)) * sc[r6];
    const float mx = wredMax(cv);
    const float e = __expf(cv-mx);
    const float s2 = wredSum(e);
    cw_s[r6][m6] = e/s2;
  }
  __syncthreads();
  {
    float fw = 0.f, bw = 0.f;
    #pragma unroll 8
    for (int m3=0;m3<64;m3++){
      const float rp = rwp_s[r6][m3];
      fw = fmaf(link_s[m6][m3], rp, fw);
      bw = fmaf(link_s[m3][m6], rp, bw);
    }
    const float rn = sc[11+3*r6]*bw + sc[12+3*r6]*fw + sc[13+3*r6]*cw_s[r6][m6];
    rwn_s[r6][m6] = rn;
    rwg[b*256 + r6*64 + m6] = rn;
  }
  __syncthreads();
  if (full != nullptr) {
    const int r8 = tid>>6, w0 = (tid&63)*8;
    float a[8];
    #pragma unroll
    for (int j=0;j<8;j++) a[j]=0.f;
    for (int m3=0;m3<64;m3++){
      const float rv_ = rwn_s[r8][m3];
      const float* mr = mem + ((size_t)b*64+m3)*512 + w0;
      const float4 p0 = *(const float4*)&mr[0];
      const float4 p1 = *(const float4*)&mr[4];
      a[0]=fmaf(rv_,p0.x,a[0]); a[1]=fmaf(rv_,p0.y,a[1]);
      a[2]=fmaf(rv_,p0.z,a[2]); a[3]=fmaf(rv_,p0.w,a[3]);
      a[4]=fmaf(rv_,p1.x,a[4]); a[5]=fmaf(rv_,p1.y,a[5]);
      a[6]=fmaf(rv_,p1.z,a[6]); a[7]=fmaf(rv_,p1.w,a[7]);
    }
    u16* dst = full + ((size_t)t*32 + b)*2560 + 512 + r8*512 + w0;
    ushort4 s0, s1;
    s0.x=f2b(a[0]); s0.y=f2b(a[1]); s0.z=f2b(a[2]); s0.w=f2b(a[3]);
    s1.x=f2b(a[4]); s1.y=f2b(a[5]); s1.z=f2b(a[6]); s1.w=f2b(a[7]);
    *(ushort4*)dst = s0;
    *(ushort4*)(dst+4) = s1;
  }
  __syncthreads();
}

struct StepArgs {
  const float* emb[2];
  const int*   seq[2];
  const float* Wx0[2]; const float* Wh0[2]; const float* bx0[2]; const float* bh0[2];
  const float* Wx1[2]; const float* Wh1[2]; const float* bx1[2]; const float* bh1[2];
  const float* Wi[2];  const float* bi[2];
  float* h0[2]; float* h1[2]; float* c0; float* c1;
  float* xi2[2]; float* oc[2];
  u16* full;
  unsigned* flags; unsigned* gen;
};

// roles: lstm0 0-63, lstm1 64-127, xi 128-184, mem 185-216, idle rest
__global__ __launch_bounds__(NTHR) void k_all(StepArgs a) {
  extern __shared__ float S[];
  const int bid = blockIdx.x;
  const int role = (bid < 64) ? 0 : (bid < 128) ? 1 : (bid < 185) ? 2 : (bid < 217) ? 3 : 4;
  unsigned ep = 0;
  if (role == 3) {
    for (int i = threadIdx.x; i < L_END; i += NTHR) S[i] = 0.f;
  }
  __syncthreads();
  for (int ph = 0; ph < 2; ++ph) {
    if (role == 0)      preload_lstm(S, bid,    a.Wx0[ph], NNIN, a.Wh0[ph]);
    else if (role == 1) preload_lstm(S, bid-64, a.Wx1[ph], 512,  a.Wh1[ph]);
    else if (role == 2) preload_xi(S, bid-128, a.Wi[ph]);
    for (int i = bid*NTHR + threadIdx.x; i < 16384; i += (int)(NBLK*NTHR)) {
      stg_c(&a.h0[0][i],0.f); stg_c(&a.h0[1][i],0.f);
      stg_c(&a.h1[0][i],0.f); stg_c(&a.h1[1][i],0.f);
    }
    if (role == 0 && threadIdx.x < 256) {
      const int cid = (threadIdx.x & 31)*512 + bid*8 + (threadIdx.x >> 5);
      a.c0[cid] = 0.f;
    } else if (role == 1 && threadIdx.x < 256) {
      const int cid = (threadIdx.x & 31)*512 + (bid-64)*8 + (threadIdx.x >> 5);
      a.c1[cid] = 0.f;
    }
    gbar6(a.flags, ++ep);
    u16* fullp = ph ? a.full : nullptr;
    for (int k = 0; k <= TT+2; ++k) {
      float* h0r = a.h0[(k+1)&1];
      float* h0w = a.h0[k&1];
      float* h1r = a.h1[k&1];
      float* h1w = a.h1[(k+1)&1];
      float* ocw = a.oc[(k+1)&1];
      float* ocr = a.oc[k&1];
      float* xiw = a.xi2[k&1];
      float* xir = a.xi2[(k+1)&1];
      if (role == 0) {
        if (k < TT)
          lstm_tile_p(S, bid, a.bx0[ph], a.bh0[ph], a.emb[ph], a.seq[ph], k,
                      nullptr, h0r, h0w, a.c0, nullptr, nullptr);
      } else if (role == 1) {
        if (k >= 1 && k <= TT)
          lstm_tile_p(S, bid-64, a.bx1[ph], a.bh1[ph], nullptr, nullptr, k-1,
                      h0r, h1r, h1w, a.c1, ocw, fullp);
      } else if (role == 2) {
        if (k >= 2 && k <= TT+1)
          xi_tile_p(S, bid-128, ocr, a.bi[ph], xiw);
      } else if (role == 3) {
        if (k >= 3)
          mem_tile_lds(S, bid-185, xir, fullp, k-3);
      }
      gbar6(a.flags, ++ep);
    }
  }
}

// ---- standalone wrappers (fallback path, 256 thr) ----
__global__ __launch_bounds__(256) void k_lstm(
    const float* Wx, int wx_stride, const float* Wh,
    const float* bx, const float* bh,
    const float* emb, const int* seq, int t, const float* xf,
    const float* hprev, float* hcur, float* cst, float* outc, u16* full)
{
  __shared__ __align__(16) float sm[SM_FLOATS];
  lstm_tile_g(sm, blockIdx.x, Wx, wx_stride, Wh, bx, bh, emb, seq, t, xf,
              hprev, hcur, cst, outc, full);
}
__global__ __launch_bounds__(256) void k_xi(
    const float* outc, const float* Wi, const float* bi, float* xi)
{
  __shared__ __align__(16) float sm[SM_FLOATS];
  xi_tile_g(sm, blockIdx.x, outc, Wi, bi, xi);
}
__global__ __launch_bounds__(256) void k_mem(
    const float* xi, float* mem, float* link, float* prec,
    float* rwg, float* wwg, float* usg, u16* full, int t)
{
  __shared__ __align__(16) float sm[SM_FLOATS];
  mem_tile_g(sm, blockIdx.x, xi, mem, link, prec, rwg, wwg, usg, full, t);
}

// y = full @ Wo.T + bo
__global__ __launch_bounds__(256) void k_y(
    const u16* __restrict__ full,
    const float* __restrict__ Wo, const float* __restrict__ bo,
    u16* __restrict__ y)
{
  __shared__ __align__(16) float As[32][136];
  const int tid = threadIdx.x;
  const int rb = blockIdx.x >> 4, cb = blockIdx.x & 15;
  const int c = tid & 31, col = cb*32 + c;
  const int b0 = (tid>>5)*4;
  float acc0=0.f,acc1=0.f,acc2=0.f,acc3=0.f;
  for (int chunk = 0; chunk < 20; ++chunk) {
    const int k0 = chunk*128;
    for (int i = tid; i < 1024; i += 256) {
      const int r = i>>5, kk = (i&31)*4;
      const float4 v = b4f(*(const ushort4*)&full[(size_t)(rb*32+r)*2560 + k0 + kk]);
      *(float4*)&As[r][kk] = v;
    }
    __syncthreads();
    const float* Wr = Wo + (size_t)col*2560 + k0;
    #pragma unroll 8
    for (int kk = 0; kk < 128; kk += 4) {
      const float4 w4 = *(const float4*)(Wr + kk);
      const float4 a0 = *(const float4*)&As[b0+0][kk];
      const float4 a1 = *(const float4*)&As[b0+1][kk];
      const float4 a2 = *(const float4*)&As[b0+2][kk];
      const float4 a3 = *(const float4*)&As[b0+3][kk];
      acc0 = fmaf(a0.x,w4.x,fmaf(a0.y,w4.y,fmaf(a0.z,w4.z,fmaf(a0.w,w4.w,acc0))));
      acc1 = fmaf(a1.x,w4.x,fmaf(a1.y,w4.y,fmaf(a1.z,w4.z,fmaf(a1.w,w4.w,acc1))));
      acc2 = fmaf(a2.x,w4.x,fmaf(a2.y,w4.y,fmaf(a2.z,w4.z,fmaf(a2.w,w4.w,acc2))));
      acc3 = fmaf(a3.x,w4.x,fmaf(a3.y,w4.y,fmaf(a3.z,w4.z,fmaf(a3.w,w4.w,acc3))));
    }
    __syncthreads();
  }
  const float bias = bo[col];
  y[(size_t)(rb*32+b0+0)*512+col] = f2b(acc0+bias);
  y[(size_t)(rb*32+b0+1)*512+col] = f2b(acc1+bias);
  y[(size_t)(rb*32+b0+2)*512+col] = f2b(acc2+bias);
  y[(size_t)(rb*32+b0+3)*512+col] = f2b(acc3+bias);
}

// logits
__global__ __launch_bounds__(256) void k_logits(
    const u16* __restrict__ y,
    const float* __restrict__ fcW, const float* __restrict__ fcb,
    float* __restrict__ outp)
{
  __shared__ __align__(16) float As[64][68];
  const int tid = threadIdx.x;
  const int bb = blockIdx.x / 157, vt = blockIdx.x % 157;
  const int tl = tid & 15, vl = tid >> 4;
  const int t0 = tl*4;
  const int vbase = vt*64 + vl*4;
  float acc[4][4];
  #pragma unroll
  for (int i=0;i<4;i++)
    #pragma unroll
    for (int j=0;j<4;j++) acc[i][j]=0.f;
  for (int chunk = 0; chunk < 8; ++chunk) {
    const int k0 = chunk*64;
    for (int i = tid; i < 1024; i += 256) {
      const int tt = i>>4, kk = (i&15)*4;
      const float4 v = b4f(*(const ushort4*)&y[((size_t)tt*32 + bb)*512 + k0 + kk]);
      *(float4*)&As[tt][kk] = v;
    }
    __syncthreads();
    for (int kk = 0; kk < 64; kk += 4) {
      const float4 a0 = *(const float4*)&As[t0+0][kk];
      const float4 a1 = *(const float4*)&As[t0+1][kk];
      const float4 a2 = *(const float4*)&As[t0+2][kk];
      const float4 a3 = *(const float4*)&As[t0+3][kk];
      #pragma unroll
      for (int vj = 0; vj < 4; ++vj) {
        const int v = vbase + vj;
        const int vc = v < VV ? v : VV-1;
        const float4 w4 = *(const float4*)(fcW + (size_t)vc*512 + k0 + kk);
        acc[vj][0] = fmaf(a0.x,w4.x,fmaf(a0.y,w4.y,fmaf(a0.z,w4.z,fmaf(a0.w,w4.w,acc[vj][0]))));
        acc[vj][1] = fmaf(a1.x,w4.x,fmaf(a1.y,w4.y,fmaf(a1.z,w4.z,fmaf(a1.w,w4.w,acc[vj][1]))));
        acc[vj][2] = fmaf(a2.x,w4.x,fmaf(a2.y,w4.y,fmaf(a2.z,w4.z,fmaf(a2.w,w4.w,acc[vj][2]))));
        acc[vj][3] = fmaf(a3.x,w4.x,fmaf(a3.y,w4.y,fmaf(a3.z,w4.z,fmaf(a3.w,w4.w,acc[vj][3]))));
      }
    }
    __syncthreads();
  }
  #pragma unroll
  for (int vj = 0; vj < 4; ++vj) {
    const int v = vbase + vj;
    if (v < VV) {
      const float bias = fcb[v];
      float4 st;
      st.x = acc[vj][0]+bias;
      st.y = acc[vj][1]+bias;
      st.z = acc[vj][2]+bias;
      st.w = acc[vj][3]+bias;
      *(float4*)&outp[(size_t)bb*640000 + (size_t)v*64 + t0] = st;
    }
  }
}

// ---- workspace layout ----
#define O_H0A 0
#define O_H0B 16384
#define O_H1A 32768
#define O_H1B 49152
#define O_C0  65536
#define O_C1  81920
#define O_MEM 98304
#define O_FLAGS 98304
#define O_XI2   102400
#define O_OC2   217824
#define O_LINK  1146880
#define O_PREC  1277952
#define O_RW    1280000
#define O_WW    1288192
#define O_USAGE 1290240
#define STATE_FLOATS 1292288
#define O_BAR  1292288
#define O_XI   1292544
#define O_OUT  1407968
#define F32_END 1424352
#define FULL_BYTE_OFF 5697408ull
#define Y_BYTE_OFF    16183168ull
#define WS_NEED       18280320ull

extern "C" void kernel_launch(void* const* d_in, const int* in_sizes, int n_in,
                              void* d_out, int out_size, void* d_ws, size_t ws_size,
                              hipStream_t stream) {
  (void)in_sizes; (void)n_in; (void)out_size;
  if (ws_size < WS_NEED) return;
  typedef const float* cf;
  cf emb_src = (cf)d_in[0], emb_tgt = (cf)d_in[1];
  cf eW[12], dWt[12];
  for (int i=0;i<12;i++){ eW[i]=(cf)d_in[2+i]; dWt[i]=(cf)d_in[14+i]; }
  cf fcW = (cf)d_in[26], fcb = (cf)d_in[27];
  const int* inp = (const int*)d_in[28];
  const int* tgt = (const int*)d_in[29];
  float* outp = (float*)d_out;
  float* w = (float*)d_ws;

  float* h0buf[2] = { w+O_H0A, w+O_H0B };
  float* h1buf[2] = { w+O_H1A, w+O_H1B };
  float* c0 = w+O_C0;  float* c1 = w+O_C1;
  float* memb = w+O_MEM;
  float* linkb = w+O_LINK; float* precb = w+O_PREC;
  float* rwb = w+O_RW;     float* wwb = w+O_WW;   float* usageb = w+O_USAGE;
  float* xib = w+O_XI;     float* outb = w+O_OUT;
  u16* fullb = (u16*)((char*)d_ws + FULL_BYTE_OFF);
  u16* yb    = (u16*)((char*)d_ws + Y_BYTE_OFF);

  hipMemsetAsync(w, 0, (size_t)(STATE_FLOATS+256)*4, stream);

  StepArgs sa;
  sa.emb[0]=emb_src; sa.emb[1]=emb_tgt;
  sa.seq[0]=inp;     sa.seq[1]=tgt;
  sa.Wx0[0]=eW[0]; sa.Wh0[0]=eW[1]; sa.bx0[0]=eW[2]; sa.bh0[0]=eW[3];
  sa.Wx1[0]=eW[4]; sa.Wh1[0]=eW[5]; sa.bx1[0]=eW[6]; sa.bh1[0]=eW[7];
  sa.Wi[0]=eW[8];  sa.bi[0]=eW[9];
  sa.Wx0[1]=dWt[0]; sa.Wh0[1]=dWt[1]; sa.bx0[1]=dWt[2]; sa.bh0[1]=dWt[3];
  sa.Wx1[1]=dWt[4]; sa.Wh1[1]=dWt[5]; sa.bx1[1]=dWt[6]; sa.bh1[1]=dWt[7];
  sa.Wi[1]=dWt[8];  sa.bi[1]=dWt[9];
  sa.h0[0]=h0buf[0]; sa.h0[1]=h0buf[1];
  sa.h1[0]=h1buf[0]; sa.h1[1]=h1buf[1];
  sa.c0=c0; sa.c1=c1;
  sa.xi2[0]=xib;      sa.xi2[1]=w+O_XI2;
  sa.oc[0]=outb;      sa.oc[1]=w+O_OC2;
  sa.full=fullb;
  sa.flags=(unsigned*)(w + O_FLAGS);
  sa.gen=(unsigned*)(w + O_BAR);

  (void)hipFuncSetAttribute((const void*)k_all,
      hipFuncAttributeMaxDynamicSharedMemorySize, DYN_LDS_BYTES);

  void* kargs[] = { &sa };
  hipError_t err = hipLaunchCooperativeKernel((const void*)k_all, dim3(NBLK), dim3(NTHR),
                                              kargs, DYN_LDS_BYTES, stream);
  if (err != hipSuccess) {
    // fallback: per-step dispatch chain (round-4-verified path, global DNC state)
    int pp = 0;
    for (int t = 0; t < TT; ++t) {
      k_lstm<<<64,256,0,stream>>>(eW[0], NNIN, eW[1], eW[2], eW[3],
                                  emb_src, inp, t, nullptr,
                                  h0buf[pp], h0buf[pp^1], c0, nullptr, nullptr);
      k_lstm<<<64,256,0,stream>>>(eW[4], 512, eW[5], eW[6], eW[7],
                                  nullptr, nullptr, t, h0buf[pp^1],
                                  h1buf[pp], h1buf[pp^1], c1, outb, nullptr);
      k_xi<<<113,256,0,stream>>>(outb, eW[8], eW[9], xib);
      k_mem<<<32,256,0,stream>>>(xib, memb, linkb, precb, rwb, wwb, usageb,
                                 nullptr, t);
      pp ^= 1;
    }
    hipMemsetAsync(w, 0, (size_t)O_MEM*4, stream);
    pp = 0;
    for (int t = 0; t < TT; ++t) {
      k_lstm<<<64,256,0,stream>>>(dWt[0], NNIN, dWt[1], dWt[2], dWt[3],
                                  emb_tgt, tgt, t, nullptr,
                                  h0buf[pp], h0buf[pp^1], c0, nullptr, nullptr);
      k_lstm<<<64,256,0,stream>>>(dWt[4], 512, dWt[5], dWt[6], dWt[7],
                                  nullptr, nullptr, t, h0buf[pp^1],
                                  h1buf[pp], h1buf[pp^1], c1, outb, fullb);
      k_xi<<<113,256,0,stream>>>(outb, dWt[8], dWt[9], xib);
      k_mem<<<32,256,0,stream>>>(xib, memb, linkb, precb, rwb, wwb, usageb,
                                 fullb, t);
      pp ^= 1;
    }
  }

  k_y<<<1024,256,0,stream>>>(fullb, dWt[10], dWt[11], yb);
  k_logits<<<32*157,256,0,stream>>>(yb, fcW, fcb, outp);
}